// Round 11
// baseline (2054.741 us; speedup 1.0000x reference)
//
#include <hip/hip_runtime.h>
#include <hip/hip_bf16.h>
#include <stdint.h>

// Problem constants
#define H_DIM 4096
#define I_DIM 11008
#define M_TOK 4096   // B*S = 2*2048

typedef __attribute__((ext_vector_type(8))) short short8;  // 8 bf16 (4 VGPRs)
typedef __attribute__((ext_vector_type(4))) float f32x4;   // 4 fp32

static __device__ __forceinline__ float bf2f(unsigned short u) {
    union { uint32_t i; float f; } v; v.i = ((uint32_t)u) << 16; return v.f;
}
static __device__ __forceinline__ unsigned short f2bf(float f) {
    union { float f; uint32_t i; } v; v.f = f;
    uint32_t r = v.i + 0x7FFF + ((v.i >> 16) & 1);   // RNE
    return (unsigned short)(r >> 16);
}

// async global->LDS, 16B per lane; LDS dest is the wave-uniform base.
static __device__ __forceinline__ void gload16(const void* g, void* l) {
    __builtin_amdgcn_global_load_lds(
        (const __attribute__((address_space(1))) void*)g,
        (__attribute__((address_space(3))) void*)l, 16, 0, 0);
}

// ---------------- small conversion kernels ----------------

__global__ void k_conv_f32_bf16(const float* __restrict__ in,
                                unsigned short* __restrict__ out, int n4) {
    int stride = gridDim.x * blockDim.x;
    for (int i = blockIdx.x * blockDim.x + threadIdx.x; i < n4; i += stride) {
        f32x4 v = ((const f32x4*)in)[i];
        uint64_t p = (uint64_t)f2bf(v[0]) | ((uint64_t)f2bf(v[1]) << 16) |
                     ((uint64_t)f2bf(v[2]) << 32) | ((uint64_t)f2bf(v[3]) << 48);
        ((uint64_t*)out)[i] = p;
    }
}

// B [32][N] f32 -> BT [N][32] bf16
__global__ void k_transposeB(const float* __restrict__ in,
                             unsigned short* __restrict__ out, int N) {
    int idx = blockIdx.x * blockDim.x + threadIdx.x;
    if (idx < N * 32) {
        int n = idx >> 5, r = idx & 31;
        out[idx] = f2bf(in[r * N + n]);
    }
}

// ---------------- W_eff prep: dequant + rank-32 LR via one MFMA step ----------------
__global__ __launch_bounds__(256) void k_wprep(
    const unsigned short* __restrict__ BT,   // [Nw][32] bf16
    const unsigned short* __restrict__ Abf,  // [Kw][32] bf16
    const int* __restrict__ q,               // [Nw][Kw] int32
    const float* __restrict__ scale,         // [Nw]
    unsigned short* __restrict__ W,          // [Nw][Kw] bf16 out
    int Nw, int Kw)
{
    __shared__ unsigned short As[128 * 32];
    __shared__ unsigned short Bs[128 * 32];
    const int tid = threadIdx.x, wid = tid >> 6, lane = tid & 63;
    const int wr = wid >> 1, wc = wid & 1;
    const int brow = blockIdx.y * 128;   // n
    const int bcol = blockIdx.x * 128;   // k
    const int srow = wid * 16 + (lane >> 2), scol = (lane & 3) * 8;

    gload16(BT + (size_t)(brow + srow) * 32 + scol,        &As[wid * 512]);
    gload16(BT + (size_t)(brow + 64 + srow) * 32 + scol,   &As[wid * 512 + 2048]);
    gload16(Abf + (size_t)(bcol + srow) * 32 + scol,       &Bs[wid * 512]);
    gload16(Abf + (size_t)(bcol + 64 + srow) * 32 + scol,  &Bs[wid * 512 + 2048]);
    __syncthreads();

    const int fr = lane & 15, kg = (lane >> 4) * 8;
    f32x4 acc[4][4] = {};
    short8 af[4], bfr[4];
#pragma unroll
    for (int i = 0; i < 4; i++)
        af[i] = *(const short8*)&As[(wr * 64 + i * 16 + fr) * 32 + kg];
#pragma unroll
    for (int j = 0; j < 4; j++)
        bfr[j] = *(const short8*)&Bs[(wc * 64 + j * 16 + fr) * 32 + kg];
#pragma unroll
    for (int i = 0; i < 4; i++)
#pragma unroll
        for (int j = 0; j < 4; j++)
            acc[i][j] = __builtin_amdgcn_mfma_f32_16x16x32_bf16(af[i], bfr[j], acc[i][j], 0, 0, 0);

    const int q4 = lane >> 4;
#pragma unroll
    for (int i = 0; i < 4; i++) {
#pragma unroll
        for (int t = 0; t < 4; t++) {
            int n = brow + wr * 64 + i * 16 + q4 * 4 + t;
            float sc = scale[n] * 0.005f;
#pragma unroll
            for (int j = 0; j < 4; j++) {
                int k = bcol + wc * 64 + j * 16 + fr;
                size_t off = (size_t)n * Kw + k;
                float w = ((float)q[off] - 7.5f) * sc + 0.02f * acc[i][j][t];
                W[off] = f2bf(w);
            }
        }
    }
}

// ---------------- main bf16 GEMM: 256x256, BK=64, 2-deep read-ahead 8-window -------
// C[M][N] = A[M][K] @ B[N][K]^T ; EPI: 0 bf16, 1 h=silu(g)*acc bf16, 2 f32
// 512 threads = 8 waves (2M x 4N); per-wave C 128x64.
// Window w = {barrier; 8 MFMA (one quadrant x one kk); reads issued EXACTLY 2
// windows before their first consuming MFMA; stage/cert per R5 calendar}.
// Window MFMA map: w0(0,0)k0 w1(0,0)k1 w2(0,1)k0 w3(0,1)k1 w4(1,1)k0 w5(1,1)k1
// w6(1,0)k0 w7(1,0)k1.  Frag reuse: A_k0 regs hold A-ih0 (w0,w2) then A-ih1
// (w4,w6) then A0' of next tile; refill ds_read is issued AFTER the consuming
// MFMA in the same window -> WAR-safe by in-order issue + register dependence.
// Read calendar: w0:B1k0  w1:B1k1  w2:A1k0  w3:A1k1  w6:A0'k0+B0'k0 (other buf)
// w7:A0'k1+B0'k1.  All issue->use distances = 2 windows (~1200cy >> ds latency).
// Stage calendar: w0 B0(t+1)->other; w2 A0(t+2)->this; w4 B1(t+2); w6 A1(t+2).
// Cert at w3-end PRE-barrier: vmcnt(2) leaves only A0(t+2) outstanding =>
// tile t+1 fully published block-wide at BAR(w4), first read of it at w6. All
// stage-over-read WARs have >=1 trailing barrier (verified per-region).
template <int EPI>
__global__ __launch_bounds__(512, 1) void k_gemm256(
    const unsigned short* __restrict__ A,   // [M][K] bf16
    const unsigned short* __restrict__ B,   // [N][K] bf16
    void* __restrict__ C,
    const unsigned short* __restrict__ Gin, // EPI==1: g buffer
    int M, int N, int K)
{
    extern __shared__ unsigned short smem[];   // 65536 elems = 128 KiB
    const int tid = threadIdx.x, wid = tid >> 6, lane = tid & 63;
    const int wr = wid >> 2, wc = wid & 3;

    // T1: bijective XCD swizzle
    const int gx = N >> 8;
    const int nwg = gx * (M >> 8);
    int orig = blockIdx.y * gx + blockIdx.x;
    int q8 = nwg >> 3, r8 = nwg & 7;
    int xcd = orig & 7, lid = orig >> 3;
    int wg = (xcd < r8 ? xcd * (q8 + 1) : r8 * (q8 + 1) + (xcd - r8) * q8) + lid;
    const int bcol = (wg % gx) << 8;
    const int brow = (wg / gx) << 8;

    // staging: quarter c covers rows [c*64 + wid*8, +8); lane l -> row l>>3,
    // LDS slot l&7, pre-swizzled global source slot (l&7)^(l>>3)
    const int rg = lane >> 3;
    const int ss = ((lane & 7) ^ rg) * 8;
    const unsigned short* aS[4];
    const unsigned short* bS[4];
#pragma unroll
    for (int c = 0; c < 4; c++) {
        int row = c * 64 + wid * 8 + rg;
        aS[c] = A + (size_t)(brow + row) * K + ss;
        bS[c] = B + (size_t)(bcol + row) * K + ss;
    }
    const int ldw = wid * 512;   // wave chunk within a 64-row quarter (elems)

    f32x4 acc[8][4] = {};
    short8 A_k0[4], A_k1[4];            // A frag set (rotates ih0 -> ih1 -> next)
    short8 B0_k0[2], B0_k1[2];          // B half0
    short8 B1_k0[2], B1_k1[2];          // B half1
    const int fr = lane & 15, qk = lane >> 4, f7 = fr & 7;
    const int NT = K >> 6;

    // per-(buffer, kk) read base pointers (literal indices only)
    const unsigned short* aP[2][2];
    const unsigned short* bP[2][2];
#pragma unroll
    for (int b = 0; b < 2; ++b)
#pragma unroll
        for (int kk = 0; kk < 2; ++kk) {
            int swz = (((kk << 2) | qk) ^ f7) << 3;
            aP[b][kk] = smem + b * 32768 + (wr * 64 + fr) * 64 + swz;
            bP[b][kk] = smem + b * 32768 + 16384 + (wc * 32 + fr) * 64 + swz;
        }

#define STG(p, k0, doff) gload16((p) + (k0), smem + (doff) + ldw)
#define SB0STG(BB, kN) { STG(bS[0], kN, (1-(BB))*32768 + 16384); \
                         STG(bS[1], kN, (1-(BB))*32768 + 20480); }
#define SA0STG(BB, k2) { STG(aS[0], k2, (BB)*32768); \
                         STG(aS[1], k2, (BB)*32768 + 4096); }
#define SB1STG(BB, k2) { STG(bS[2], k2, (BB)*32768 + 24576); \
                         STG(bS[3], k2, (BB)*32768 + 28672); }
#define SA1STG(BB, k2) { STG(aS[2], k2, (BB)*32768 + 8192); \
                         STG(aS[3], k2, (BB)*32768 + 12288); }
#define LDA4(SET, BB, IH, KK) { _Pragma("unroll") \
    for (int i4 = 0; i4 < 4; ++i4) \
        SET[i4] = *(const short8*)&aP[BB][KK][(IH)*8192 + i4*1024]; }
#define LDB2(SET, BB, JH, KK) { _Pragma("unroll") \
    for (int j2 = 0; j2 < 2; ++j2) \
        SET[j2] = *(const short8*)&bP[BB][KK][(JH)*8192 + j2*1024]; }
#define MFQ8(AF, BF, IH, JH) { __builtin_amdgcn_s_setprio(1); \
    _Pragma("unroll") for (int i4 = 0; i4 < 4; ++i4) \
    _Pragma("unroll") for (int j2 = 0; j2 < 2; ++j2) \
        acc[(IH)*4+i4][(JH)*2+j2] = __builtin_amdgcn_mfma_f32_16x16x32_bf16( \
            AF[i4], BF[j2], acc[(IH)*4+i4][(JH)*2+j2], 0, 0, 0); \
    __builtin_amdgcn_s_setprio(0); }
#define BAR() __builtin_amdgcn_s_barrier()

// One K-tile (8 windows). BB: buffer (literal). SB0: stage B0(t+1). S2: stage
// t+2 trio. CRT: 0 none / 1 vmcnt(2) / 2 vmcnt(0). RN: read next-tile A0'/B0'.
#define TILE(BB, SB0, S2, CRT, RN, kN, k2) { \
    /* w0 */ \
    BAR(); \
    MFQ8(A_k0, B0_k0, 0, 0); \
    LDB2(B1_k0, BB, 1, 0); \
    if (SB0) { SB0STG(BB, kN); } \
    /* w1 */ \
    BAR(); \
    MFQ8(A_k1, B0_k1, 0, 0); \
    LDB2(B1_k1, BB, 1, 1); \
    /* w2 */ \
    BAR(); \
    MFQ8(A_k0, B1_k0, 0, 1); \
    LDA4(A_k0, BB, 1, 0); \
    if (S2) { SA0STG(BB, k2); } \
    /* w3 */ \
    BAR(); \
    MFQ8(A_k1, B1_k1, 0, 1); \
    LDA4(A_k1, BB, 1, 1); \
    if (CRT == 1) asm volatile("s_waitcnt vmcnt(2)" ::: "memory"); \
    if (CRT == 2) asm volatile("s_waitcnt vmcnt(0)" ::: "memory"); \
    /* w4 */ \
    BAR(); \
    MFQ8(A_k0, B1_k0, 1, 1); \
    if (S2) { SB1STG(BB, k2); } \
    /* w5 */ \
    BAR(); \
    MFQ8(A_k1, B1_k1, 1, 1); \
    /* w6 */ \
    BAR(); \
    MFQ8(A_k0, B0_k0, 1, 0); \
    if (RN) { LDA4(A_k0, 1-(BB), 0, 0); LDB2(B0_k0, 1-(BB), 0, 0); } \
    if (S2) { SA1STG(BB, k2); } \
    /* w7 */ \
    BAR(); \
    MFQ8(A_k1, B0_k1, 1, 0); \
    if (RN) { LDA4(A_k1, 1-(BB), 0, 1); LDB2(B0_k1, 1-(BB), 0, 1); } \
}

    // prologue: stage tile0 full + tile1 {A0,B1,A1} (14 loads; B0(1) at w0(t0)).
    SA0STG(0, 0); SB0STG(1, 0); SB1STG(0, 0); SA1STG(0, 0);
    SA0STG(1, 64); SB1STG(1, 64); SA1STG(1, 64);
    asm volatile("s_waitcnt vmcnt(6)" ::: "memory");   // tile 0 landed
    BAR();
    // "w6/w7(t=-1)" pre-reads: tile0 A0 + B0, both kk (12 reads)
    LDA4(A_k0, 0, 0, 0); LDB2(B0_k0, 0, 0, 0);
    LDA4(A_k1, 0, 0, 1); LDB2(B0_k1, 0, 0, 1);

    for (int t = 0; t < NT - 2; t += 2) {
        TILE(0, 1, 1, 1, 1, (t + 1) << 6, (t + 2) << 6);
        TILE(1, 1, 1, 1, 1, (t + 2) << 6, (t + 3) << 6);
    }
    TILE(0, 1, 0, 2, 1, (NT - 1) << 6, 0);   // t = NT-2
    TILE(1, 0, 0, 0, 0, 0, 0);               // t = NT-1

#undef TILE
#undef BAR
#undef MFQ8
#undef LDB2
#undef LDA4
#undef SA1STG
#undef SB1STG
#undef SA0STG
#undef SB0STG
#undef STG

    // epilogue
    const int q4 = lane >> 4;
#pragma unroll
    for (int i = 0; i < 8; ++i) {
#pragma unroll
        for (int j = 0; j < 4; ++j) {
#pragma unroll
            for (int tt = 0; tt < 4; ++tt) {
                int m = brow + (i >> 2) * 128 + wr * 64 + (i & 3) * 16 + q4 * 4 + tt;
                int n = bcol + (j >> 1) * 128 + wc * 32 + (j & 1) * 16 + fr;
                size_t off = (size_t)m * N + n;
                float v = acc[i][j][tt];
                if (EPI == 0) {
                    ((unsigned short*)C)[off] = f2bf(v);
                } else if (EPI == 1) {
                    float g = bf2f(Gin[off]);
                    float s = g / (1.0f + __expf(-g));   // silu(g)
                    ((unsigned short*)C)[off] = f2bf(s * v);
                } else {
                    ((float*)C)[off] = v;
                }
            }
        }
    }
}

// ---------------- host launch ----------------
extern "C" void kernel_launch(void* const* d_in, const int* in_sizes, int n_in,
                              void* d_out, int out_size, void* d_ws, size_t ws_size,
                              hipStream_t stream) {
    (void)in_sizes; (void)n_in; (void)out_size; (void)ws_size;
    const float* x          = (const float*)d_in[0];
    const int*   gate_q     = (const int*)d_in[1];
    const float* gate_scale = (const float*)d_in[2];
    const float* gate_A     = (const float*)d_in[3];
    const float* gate_B     = (const float*)d_in[4];
    const int*   up_q       = (const int*)d_in[5];
    const float* up_scale   = (const float*)d_in[6];
    const float* up_A       = (const float*)d_in[7];
    const float* up_B       = (const float*)d_in[8];
    const int*   down_q     = (const int*)d_in[9];
    const float* down_scale = (const float*)d_in[10];
    const float* down_A     = (const float*)d_in[11];
    const float* down_B     = (const float*)d_in[12];

    char* ws = (char*)d_ws;
    size_t off = 0;
    auto alloc = [&](size_t bytes) {
        void* p = ws + off; off += (bytes + 255) & ~(size_t)255; return p;
    };
    unsigned short* xbf  = (unsigned short*)alloc((size_t)M_TOK * H_DIM * 2);
    unsigned short* wg   = (unsigned short*)alloc((size_t)I_DIM * H_DIM * 2);
    unsigned short* wu   = (unsigned short*)alloc((size_t)I_DIM * H_DIM * 2);
    unsigned short* wd   = (unsigned short*)alloc((size_t)H_DIM * I_DIM * 2);
    unsigned short* gbuf = (unsigned short*)alloc((size_t)M_TOK * I_DIM * 2);
    unsigned short* AgBf = (unsigned short*)alloc((size_t)H_DIM * 32 * 2);
    unsigned short* AuBf = (unsigned short*)alloc((size_t)H_DIM * 32 * 2);
    unsigned short* AdBf = (unsigned short*)alloc((size_t)I_DIM * 32 * 2);
    unsigned short* BgT  = (unsigned short*)alloc((size_t)I_DIM * 32 * 2);
    unsigned short* BuT  = (unsigned short*)alloc((size_t)I_DIM * 32 * 2);
    unsigned short* BdT  = (unsigned short*)alloc((size_t)H_DIM * 32 * 2);

    (void)hipFuncSetAttribute((const void*)k_gemm256<0>,
        hipFuncAttributeMaxDynamicSharedMemorySize, 131072);
    (void)hipFuncSetAttribute((const void*)k_gemm256<1>,
        hipFuncAttributeMaxDynamicSharedMemorySize, 131072);
    (void)hipFuncSetAttribute((const void*)k_gemm256<2>,
        hipFuncAttributeMaxDynamicSharedMemorySize, 131072);

    // small conversions
    k_conv_f32_bf16<<<128, 256, 0, stream>>>(gate_A, AgBf, (H_DIM * 32) / 4);
    k_conv_f32_bf16<<<128, 256, 0, stream>>>(up_A,   AuBf, (H_DIM * 32) / 4);
    k_conv_f32_bf16<<<344, 256, 0, stream>>>(down_A, AdBf, (I_DIM * 32) / 4);
    k_transposeB<<<(I_DIM * 32 + 255) / 256, 256, 0, stream>>>(gate_B, BgT, I_DIM);
    k_transposeB<<<(I_DIM * 32 + 255) / 256, 256, 0, stream>>>(up_B,   BuT, I_DIM);
    k_transposeB<<<(H_DIM * 32 + 255) / 256, 256, 0, stream>>>(down_B, BdT, H_DIM);
    k_conv_f32_bf16<<<2048, 256, 0, stream>>>(x, xbf, (M_TOK * H_DIM) / 4);

    // W_eff = dequant + 0.02*(A@B)^T   (bf16)
    k_wprep<<<dim3(H_DIM / 128, I_DIM / 128), 256, 0, stream>>>(BgT, AgBf, gate_q, gate_scale, wg, I_DIM, H_DIM);
    k_wprep<<<dim3(H_DIM / 128, I_DIM / 128), 256, 0, stream>>>(BuT, AuBf, up_q,   up_scale,   wu, I_DIM, H_DIM);
    k_wprep<<<dim3(I_DIM / 128, H_DIM / 128), 256, 0, stream>>>(BdT, AdBf, down_q, down_scale, wd, H_DIM, I_DIM);

    // g = x @ Wg^T          (bf16 out)
    k_gemm256<0><<<dim3(I_DIM / 256, M_TOK / 256), 512, 131072, stream>>>(xbf, wg, gbuf, nullptr, M_TOK, I_DIM, H_DIM);
    // h = silu(g) * (x @ Wu^T)   (in-place over g)
    k_gemm256<1><<<dim3(I_DIM / 256, M_TOK / 256), 512, 131072, stream>>>(xbf, wu, gbuf, gbuf, M_TOK, I_DIM, H_DIM);
    // out = h @ Wd^T        (f32)
    k_gemm256<2><<<dim3(H_DIM / 256, M_TOK / 256), 512, 131072, stream>>>(gbuf, wd, d_out, nullptr, M_TOK, H_DIM, I_DIM);
}

// Round 12
// 1134.284 us; speedup vs baseline: 1.8115x; 1.8115x over previous
//
#include <hip/hip_runtime.h>
#include <hip/hip_bf16.h>
#include <stdint.h>

// Problem constants
#define H_DIM 4096
#define I_DIM 11008
#define M_TOK 4096   // B*S = 2*2048

typedef __attribute__((ext_vector_type(8))) short short8;  // 8 bf16 (4 VGPRs)
typedef __attribute__((ext_vector_type(4))) float f32x4;   // 4 fp32

static __device__ __forceinline__ float bf2f(unsigned short u) {
    union { uint32_t i; float f; } v; v.i = ((uint32_t)u) << 16; return v.f;
}
static __device__ __forceinline__ unsigned short f2bf(float f) {
    union { float f; uint32_t i; } v; v.f = f;
    uint32_t r = v.i + 0x7FFF + ((v.i >> 16) & 1);   // RNE
    return (unsigned short)(r >> 16);
}

// async global->LDS, 16B per lane; LDS dest is the wave-uniform base.
static __device__ __forceinline__ void gload16(const void* g, void* l) {
    __builtin_amdgcn_global_load_lds(
        (const __attribute__((address_space(1))) void*)g,
        (__attribute__((address_space(3))) void*)l, 16, 0, 0);
}

// ---------------- small conversion kernels ----------------

__global__ void k_conv_f32_bf16(const float* __restrict__ in,
                                unsigned short* __restrict__ out, int n4) {
    int stride = gridDim.x * blockDim.x;
    for (int i = blockIdx.x * blockDim.x + threadIdx.x; i < n4; i += stride) {
        f32x4 v = ((const f32x4*)in)[i];
        uint64_t p = (uint64_t)f2bf(v[0]) | ((uint64_t)f2bf(v[1]) << 16) |
                     ((uint64_t)f2bf(v[2]) << 32) | ((uint64_t)f2bf(v[3]) << 48);
        ((uint64_t*)out)[i] = p;
    }
}

// B [32][N] f32 -> BT [N][32] bf16
__global__ void k_transposeB(const float* __restrict__ in,
                             unsigned short* __restrict__ out, int N) {
    int idx = blockIdx.x * blockDim.x + threadIdx.x;
    if (idx < N * 32) {
        int n = idx >> 5, r = idx & 31;
        out[idx] = f2bf(in[r * N + n]);
    }
}

// ---------------- W_eff prep: dequant + rank-32 LR via one MFMA step ----------------
__global__ __launch_bounds__(256) void k_wprep(
    const unsigned short* __restrict__ BT,   // [Nw][32] bf16
    const unsigned short* __restrict__ Abf,  // [Kw][32] bf16
    const int* __restrict__ q,               // [Nw][Kw] int32
    const float* __restrict__ scale,         // [Nw]
    unsigned short* __restrict__ W,          // [Nw][Kw] bf16 out
    int Nw, int Kw)
{
    __shared__ unsigned short As[128 * 32];
    __shared__ unsigned short Bs[128 * 32];
    const int tid = threadIdx.x, wid = tid >> 6, lane = tid & 63;
    const int wr = wid >> 1, wc = wid & 1;
    const int brow = blockIdx.y * 128;   // n
    const int bcol = blockIdx.x * 128;   // k
    const int srow = wid * 16 + (lane >> 2), scol = (lane & 3) * 8;

    gload16(BT + (size_t)(brow + srow) * 32 + scol,        &As[wid * 512]);
    gload16(BT + (size_t)(brow + 64 + srow) * 32 + scol,   &As[wid * 512 + 2048]);
    gload16(Abf + (size_t)(bcol + srow) * 32 + scol,       &Bs[wid * 512]);
    gload16(Abf + (size_t)(bcol + 64 + srow) * 32 + scol,  &Bs[wid * 512 + 2048]);
    __syncthreads();

    const int fr = lane & 15, kg = (lane >> 4) * 8;
    f32x4 acc[4][4] = {};
    short8 af[4], bfr[4];
#pragma unroll
    for (int i = 0; i < 4; i++)
        af[i] = *(const short8*)&As[(wr * 64 + i * 16 + fr) * 32 + kg];
#pragma unroll
    for (int j = 0; j < 4; j++)
        bfr[j] = *(const short8*)&Bs[(wc * 64 + j * 16 + fr) * 32 + kg];
#pragma unroll
    for (int i = 0; i < 4; i++)
#pragma unroll
        for (int j = 0; j < 4; j++)
            acc[i][j] = __builtin_amdgcn_mfma_f32_16x16x32_bf16(af[i], bfr[j], acc[i][j], 0, 0, 0);

    const int q4 = lane >> 4;
#pragma unroll
    for (int i = 0; i < 4; i++) {
#pragma unroll
        for (int t = 0; t < 4; t++) {
            int n = brow + wr * 64 + i * 16 + q4 * 4 + t;
            float sc = scale[n] * 0.005f;
#pragma unroll
            for (int j = 0; j < 4; j++) {
                int k = bcol + wc * 64 + j * 16 + fr;
                size_t off = (size_t)n * Kw + k;
                float w = ((float)q[off] - 7.5f) * sc + 0.02f * acc[i][j][t];
                W[off] = f2bf(w);
            }
        }
    }
}

// ================== shared GEMM schedule machinery (R5 = best-known) ==============
// 512 threads = 8 waves (2M x 4N); per-wave C 128x64; 256x(B-)256 tile; BK=64.
// 8 windows/tile; reads for window w+1 issued pre-barrier in window w; MFMA
// clusters of 8; stage calendar P0:B0(t+1) P2:A0(t+2) P4:B1(t+2) P6:A1(t+2);
// cert vmcnt(2) at P4-top (pre-barrier, R6-safe). Verified at 351us/GEMM.

#define STG(p, k0, doff) gload16((p) + (k0), smem + (doff) + ldw)
#define LDA8(dst, P, IH) { _Pragma("unroll") \
    for (int i4 = 0; i4 < 4; ++i4) dst[i4] = *(const short8*)&(P)[(IH)*8192 + i4*1024]; }
#define LDB4(dst, P, JH) { _Pragma("unroll") \
    for (int j2 = 0; j2 < 2; ++j2) dst[j2] = *(const short8*)&(P)[(JH)*8192 + j2*1024]; }
#define MF8(AF, BF, IH, JH) { __builtin_amdgcn_s_setprio(1); \
    _Pragma("unroll") for (int i4 = 0; i4 < 4; ++i4) \
    _Pragma("unroll") for (int j2 = 0; j2 < 2; ++j2) \
        acc[(IH)*4+i4][(JH)*2+j2] = __builtin_amdgcn_mfma_f32_16x16x32_bf16( \
            AF[i4], BF[j2], acc[(IH)*4+i4][(JH)*2+j2], 0, 0, 0); \
    __builtin_amdgcn_s_setprio(0); }

#define TILE(BB, t, S2, SB0, CERT, RNEXT) { \
    const int kN = ((t) + 1) << 6, kN2 = ((t) + 2) << 6; \
    LDA8(afY, aP[BB][1], 0); LDB4(bfY, bP[BB][1], 0); \
    __builtin_amdgcn_s_barrier(); \
    if (SB0) { STG(bS[0], kN, (1-(BB))*32768 + 16384); \
               STG(bS[1], kN, (1-(BB))*32768 + 20480); } \
    MF8(afX, bfX, 0, 0); \
    LDB4(bfX, bP[BB][0], 1); \
    __builtin_amdgcn_s_barrier(); \
    MF8(afY, bfY, 0, 0); \
    LDB4(bfY, bP[BB][1], 1); \
    __builtin_amdgcn_s_barrier(); \
    if (S2) { STG(aS[0], kN2, (BB)*32768); STG(aS[1], kN2, (BB)*32768 + 4096); } \
    MF8(afX, bfX, 0, 1); \
    LDA8(afX, aP[BB][0], 1); \
    __builtin_amdgcn_s_barrier(); \
    MF8(afY, bfY, 0, 1); \
    LDA8(afY, aP[BB][1], 1); \
    if (CERT == 1) asm volatile("s_waitcnt vmcnt(2)" ::: "memory"); \
    if (CERT == 2) asm volatile("s_waitcnt vmcnt(0)" ::: "memory"); \
    __builtin_amdgcn_s_barrier(); \
    if (S2) { STG(bS[2], kN2, (BB)*32768 + 24576); STG(bS[3], kN2, (BB)*32768 + 28672); } \
    MF8(afX, bfX, 1, 1); \
    LDB4(bfX, bP[BB][0], 0); \
    __builtin_amdgcn_s_barrier(); \
    MF8(afY, bfY, 1, 1); \
    LDB4(bfY, bP[BB][1], 0); \
    __builtin_amdgcn_s_barrier(); \
    if (S2) { STG(aS[2], kN2, (BB)*32768 + 8192); STG(aS[3], kN2, (BB)*32768 + 12288); } \
    MF8(afX, bfX, 1, 0); \
    if (RNEXT) { LDA8(afX, aP[1-(BB)][0], 0); LDB4(bfX, bP[1-(BB)][0], 0); } \
    __builtin_amdgcn_s_barrier(); \
    MF8(afY, bfY, 1, 0); \
}

#define GEMM_BODY(K_) { \
    const int NT = (K_) >> 6; \
    STG(aS[0], 0, 0);      STG(aS[1], 0, 4096); \
    STG(bS[0], 0, 16384);  STG(bS[1], 0, 20480); \
    STG(bS[2], 0, 24576);  STG(bS[3], 0, 28672); \
    STG(aS[2], 0, 8192);   STG(aS[3], 0, 12288); \
    STG(aS[0], 64, 32768);         STG(aS[1], 64, 32768 + 4096); \
    STG(bS[2], 64, 32768 + 24576); STG(bS[3], 64, 32768 + 28672); \
    STG(aS[2], 64, 32768 + 8192);  STG(aS[3], 64, 32768 + 12288); \
    asm volatile("s_waitcnt vmcnt(6)" ::: "memory"); \
    __builtin_amdgcn_s_barrier(); \
    LDA8(afX, aP[0][0], 0); LDB4(bfX, bP[0][0], 0); \
    int t = 0; \
    for (; t + 4 <= NT; t += 2) { \
        TILE(0, t,     1, 1, 1, 1); \
        TILE(1, t + 1, 1, 1, 1, 1); \
    } \
    TILE(0, NT - 2, 0, 1, 2, 1); \
    TILE(1, NT - 1, 0, 0, 0, 0); \
}

// ---------------- fused gate+up GEMM: h = silu(x@Wg^T) * (x@Wu^T) ----------------
// Block: 256 M-rows x 128 N-cols of BOTH g and u. B-LDS rows 0-127 = wg chunk
// (jh=0 quadrants -> g), rows 128-255 = wu chunk (jh=1 -> u), SAME output cols.
__global__ __launch_bounds__(512, 1) void k_gemmfused(
    const unsigned short* __restrict__ A,    // [M][K] bf16 (x)
    const unsigned short* __restrict__ Wg,   // [NI][K] bf16
    const unsigned short* __restrict__ Wu,   // [NI][K] bf16
    unsigned short* __restrict__ H,          // [M][NI] bf16 out
    int M, int NI, int K)
{
    extern __shared__ unsigned short smem[];   // 128 KiB
    const int tid = threadIdx.x, wid = tid >> 6, lane = tid & 63;
    const int wr = wid >> 2, wc = wid & 3;

    const int gx = NI >> 7;                    // 128-wide output tiles
    const int nwg = gx * (M >> 8);
    int orig = blockIdx.y * gx + blockIdx.x;
    int q8 = nwg >> 3, r8 = nwg & 7;
    int xcd = orig & 7, lid = orig >> 3;
    int wg = (xcd < r8 ? xcd * (q8 + 1) : r8 * (q8 + 1) + (xcd - r8) * q8) + lid;
    const int bcol = (wg % gx) << 7;
    const int brow = (wg / gx) << 8;

    const int rg = lane >> 3;
    const int ss = ((lane & 7) ^ rg) * 8;
    const unsigned short* aS[4];
    const unsigned short* bS[4];
#pragma unroll
    for (int c = 0; c < 4; c++) {
        int arow = c * 64 + wid * 8 + rg;
        aS[c] = A + (size_t)(brow + arow) * K + ss;
    }
#pragma unroll
    for (int c = 0; c < 2; c++) {
        int nrow = c * 64 + wid * 8 + rg;      // 0..127 within the 128-chunk
        bS[c]     = Wg + (size_t)(bcol + nrow) * K + ss;
        bS[c + 2] = Wu + (size_t)(bcol + nrow) * K + ss;
    }
    const int ldw = wid * 512;

    f32x4 acc[8][4] = {};
    short8 afX[4], afY[4], bfX[2], bfY[2];
    const int fr = lane & 15, qk = lane >> 4, f7 = fr & 7;

    const unsigned short* aP[2][2];
    const unsigned short* bP[2][2];
#pragma unroll
    for (int b = 0; b < 2; ++b)
#pragma unroll
        for (int kk = 0; kk < 2; ++kk) {
            int swz = (((kk << 2) | qk) ^ f7) << 3;
            aP[b][kk] = smem + b * 32768 + (wr * 64 + fr) * 64 + swz;
            bP[b][kk] = smem + b * 32768 + 16384 + (wc * 32 + fr) * 64 + swz;
        }

    GEMM_BODY(K);

    // epilogue: acc[i][j2] = g, acc[i][2+j2] = u at the same (m, col).
    const int q4 = lane >> 4;
#pragma unroll
    for (int i = 0; i < 8; ++i) {
#pragma unroll
        for (int j2 = 0; j2 < 2; ++j2) {
#pragma unroll
            for (int tt = 0; tt < 4; ++tt) {
                int m = brow + (i >> 2) * 128 + wr * 64 + (i & 3) * 16 + q4 * 4 + tt;
                int n = bcol + wc * 32 + j2 * 16 + fr;
                float g = acc[i][j2][tt];
                float u = acc[i][2 + j2][tt];
                float s = g / (1.0f + __expf(-g));   // silu(g)
                H[(size_t)m * NI + n] = f2bf(s * u);
            }
        }
    }
}

// ---------------- down GEMM: C[M][N] = A[M][K] @ B[N][K]^T, f32 out --------------
__global__ __launch_bounds__(512, 1) void k_gemmdown(
    const unsigned short* __restrict__ A,   // [M][K] bf16 (h)
    const unsigned short* __restrict__ B,   // [N][K] bf16 (wd)
    float* __restrict__ C,                  // [M][N] f32
    int M, int N, int K)
{
    extern __shared__ unsigned short smem[];   // 128 KiB
    const int tid = threadIdx.x, wid = tid >> 6, lane = tid & 63;
    const int wr = wid >> 2, wc = wid & 3;

    const int gx = N >> 8;
    const int nwg = gx * (M >> 8);
    int orig = blockIdx.y * gx + blockIdx.x;
    int q8 = nwg >> 3, r8 = nwg & 7;
    int xcd = orig & 7, lid = orig >> 3;
    int wg = (xcd < r8 ? xcd * (q8 + 1) : r8 * (q8 + 1) + (xcd - r8) * q8) + lid;
    const int bcol = (wg % gx) << 8;
    const int brow = (wg / gx) << 8;

    const int rg = lane >> 3;
    const int ss = ((lane & 7) ^ rg) * 8;
    const unsigned short* aS[4];
    const unsigned short* bS[4];
#pragma unroll
    for (int c = 0; c < 4; c++) {
        int row = c * 64 + wid * 8 + rg;
        aS[c] = A + (size_t)(brow + row) * K + ss;
        bS[c] = B + (size_t)(bcol + row) * K + ss;
    }
    const int ldw = wid * 512;

    f32x4 acc[8][4] = {};
    short8 afX[4], afY[4], bfX[2], bfY[2];
    const int fr = lane & 15, qk = lane >> 4, f7 = fr & 7;

    const unsigned short* aP[2][2];
    const unsigned short* bP[2][2];
#pragma unroll
    for (int b = 0; b < 2; ++b)
#pragma unroll
        for (int kk = 0; kk < 2; ++kk) {
            int swz = (((kk << 2) | qk) ^ f7) << 3;
            aP[b][kk] = smem + b * 32768 + (wr * 64 + fr) * 64 + swz;
            bP[b][kk] = smem + b * 32768 + 16384 + (wc * 32 + fr) * 64 + swz;
        }

    GEMM_BODY(K);

    const int q4 = lane >> 4;
#pragma unroll
    for (int i = 0; i < 8; ++i) {
#pragma unroll
        for (int j = 0; j < 4; ++j) {
#pragma unroll
            for (int tt = 0; tt < 4; ++tt) {
                int m = brow + (i >> 2) * 128 + wr * 64 + (i & 3) * 16 + q4 * 4 + tt;
                int n = bcol + (j >> 1) * 128 + wc * 32 + (j & 1) * 16 + fr;
                C[(size_t)m * N + n] = acc[i][j][tt];
            }
        }
    }
}

// ---------------- host launch ----------------
extern "C" void kernel_launch(void* const* d_in, const int* in_sizes, int n_in,
                              void* d_out, int out_size, void* d_ws, size_t ws_size,
                              hipStream_t stream) {
    (void)in_sizes; (void)n_in; (void)out_size; (void)ws_size;
    const float* x          = (const float*)d_in[0];
    const int*   gate_q     = (const int*)d_in[1];
    const float* gate_scale = (const float*)d_in[2];
    const float* gate_A     = (const float*)d_in[3];
    const float* gate_B     = (const float*)d_in[4];
    const int*   up_q       = (const int*)d_in[5];
    const float* up_scale   = (const float*)d_in[6];
    const float* up_A       = (const float*)d_in[7];
    const float* up_B       = (const float*)d_in[8];
    const int*   down_q     = (const int*)d_in[9];
    const float* down_scale = (const float*)d_in[10];
    const float* down_A     = (const float*)d_in[11];
    const float* down_B     = (const float*)d_in[12];

    char* ws = (char*)d_ws;
    size_t off = 0;
    auto alloc = [&](size_t bytes) {
        void* p = ws + off; off += (bytes + 255) & ~(size_t)255; return p;
    };
    unsigned short* xbf  = (unsigned short*)alloc((size_t)M_TOK * H_DIM * 2);
    unsigned short* wgm  = (unsigned short*)alloc((size_t)I_DIM * H_DIM * 2);
    unsigned short* wum  = (unsigned short*)alloc((size_t)I_DIM * H_DIM * 2);
    unsigned short* wdm  = (unsigned short*)alloc((size_t)H_DIM * I_DIM * 2);
    unsigned short* hbuf = (unsigned short*)alloc((size_t)M_TOK * I_DIM * 2);
    unsigned short* AgBf = (unsigned short*)alloc((size_t)H_DIM * 32 * 2);
    unsigned short* AuBf = (unsigned short*)alloc((size_t)H_DIM * 32 * 2);
    unsigned short* AdBf = (unsigned short*)alloc((size_t)I_DIM * 32 * 2);
    unsigned short* BgT  = (unsigned short*)alloc((size_t)I_DIM * 32 * 2);
    unsigned short* BuT  = (unsigned short*)alloc((size_t)I_DIM * 32 * 2);
    unsigned short* BdT  = (unsigned short*)alloc((size_t)H_DIM * 32 * 2);

    (void)hipFuncSetAttribute((const void*)k_gemmfused,
        hipFuncAttributeMaxDynamicSharedMemorySize, 131072);
    (void)hipFuncSetAttribute((const void*)k_gemmdown,
        hipFuncAttributeMaxDynamicSharedMemorySize, 131072);

    // small conversions
    k_conv_f32_bf16<<<128, 256, 0, stream>>>(gate_A, AgBf, (H_DIM * 32) / 4);
    k_conv_f32_bf16<<<128, 256, 0, stream>>>(up_A,   AuBf, (H_DIM * 32) / 4);
    k_conv_f32_bf16<<<344, 256, 0, stream>>>(down_A, AdBf, (I_DIM * 32) / 4);
    k_transposeB<<<(I_DIM * 32 + 255) / 256, 256, 0, stream>>>(gate_B, BgT, I_DIM);
    k_transposeB<<<(I_DIM * 32 + 255) / 256, 256, 0, stream>>>(up_B,   BuT, I_DIM);
    k_transposeB<<<(H_DIM * 32 + 255) / 256, 256, 0, stream>>>(down_B, BdT, H_DIM);
    k_conv_f32_bf16<<<2048, 256, 0, stream>>>(x, xbf, (M_TOK * H_DIM) / 4);

    // W_eff = dequant + 0.02*(A@B)^T   (bf16)
    k_wprep<<<dim3(H_DIM / 128, I_DIM / 128), 256, 0, stream>>>(BgT, AgBf, gate_q, gate_scale, wgm, I_DIM, H_DIM);
    k_wprep<<<dim3(H_DIM / 128, I_DIM / 128), 256, 0, stream>>>(BuT, AuBf, up_q,   up_scale,   wum, I_DIM, H_DIM);
    k_wprep<<<dim3(I_DIM / 128, H_DIM / 128), 256, 0, stream>>>(BdT, AdBf, down_q, down_scale, wdm, H_DIM, I_DIM);

    // h = silu(x @ Wg^T) * (x @ Wu^T)   (fused, bf16 out)
    k_gemmfused<<<dim3(I_DIM / 128, M_TOK / 256), 512, 131072, stream>>>(
        xbf, wgm, wum, hbuf, M_TOK, I_DIM, H_DIM);
    // out = h @ Wd^T   (f32)
    k_gemmdown<<<dim3(H_DIM / 256, M_TOK / 256), 512, 131072, stream>>>(
        hbuf, wdm, (float*)d_out, M_TOK, H_DIM, I_DIM);
}

// Round 13
// 1124.676 us; speedup vs baseline: 1.8270x; 1.0085x over previous
//
#include <hip/hip_runtime.h>
#include <hip/hip_bf16.h>
#include <stdint.h>

// Problem constants
#define H_DIM 4096
#define I_DIM 11008
#define M_TOK 4096   // B*S = 2*2048

typedef __attribute__((ext_vector_type(8))) short short8;  // 8 bf16 (4 VGPRs)
typedef __attribute__((ext_vector_type(4))) float f32x4;   // 4 fp32

static __device__ __forceinline__ float bf2f(unsigned short u) {
    union { uint32_t i; float f; } v; v.i = ((uint32_t)u) << 16; return v.f;
}
static __device__ __forceinline__ unsigned short f2bf(float f) {
    union { float f; uint32_t i; } v; v.f = f;
    uint32_t r = v.i + 0x7FFF + ((v.i >> 16) & 1);   // RNE
    return (unsigned short)(r >> 16);
}

// async global->LDS, 16B per lane; LDS dest is the wave-uniform base.
static __device__ __forceinline__ void gload16(const void* g, void* l) {
    __builtin_amdgcn_global_load_lds(
        (const __attribute__((address_space(1))) void*)g,
        (__attribute__((address_space(3))) void*)l, 16, 0, 0);
}

// ---------------- merged prep kernel: all f32->bf16 conversions + B transposes ----
__global__ void k_prep_all(
    const float* __restrict__ x,
    const float* __restrict__ gA, const float* __restrict__ uA,
    const float* __restrict__ dA,
    const float* __restrict__ gB, const float* __restrict__ uB,
    const float* __restrict__ dB,
    unsigned short* __restrict__ xbf,
    unsigned short* __restrict__ AgBf, unsigned short* __restrict__ AuBf,
    unsigned short* __restrict__ AdBf,
    unsigned short* __restrict__ BgT, unsigned short* __restrict__ BuT,
    unsigned short* __restrict__ BdT)
{
    const int XN4 = (M_TOK * H_DIM) / 4;
    const int GA4 = (H_DIM * 32) / 4;
    const int DA4 = (I_DIM * 32) / 4;
    const int TOT4 = XN4 + 2 * GA4 + DA4;
    const int stride = gridDim.x * blockDim.x;
    for (int i = blockIdx.x * blockDim.x + threadIdx.x; i < TOT4; i += stride) {
        int j = i; const float* src; unsigned short* dst;
        if (j < XN4) { src = x; dst = xbf; }
        else if ((j -= XN4) < GA4) { src = gA; dst = AgBf; }
        else if ((j -= GA4) < GA4) { src = uA; dst = AuBf; }
        else { j -= GA4; src = dA; dst = AdBf; }
        f32x4 v = ((const f32x4*)src)[j];
        uint64_t p = (uint64_t)f2bf(v[0]) | ((uint64_t)f2bf(v[1]) << 16) |
                     ((uint64_t)f2bf(v[2]) << 32) | ((uint64_t)f2bf(v[3]) << 48);
        ((uint64_t*)dst)[j] = p;
    }
    const int TBI = I_DIM * 32, TBH = H_DIM * 32;
    const int TOTT = 2 * TBI + TBH;
    for (int i = blockIdx.x * blockDim.x + threadIdx.x; i < TOTT; i += stride) {
        int j = i; const float* src; unsigned short* dst; int N;
        if (j < TBI) { src = gB; dst = BgT; N = I_DIM; }
        else if ((j -= TBI) < TBI) { src = uB; dst = BuT; N = I_DIM; }
        else { j -= TBI; src = dB; dst = BdT; N = H_DIM; }
        int n = j >> 5, r = j & 31;
        dst[j] = f2bf(src[r * N + n]);
    }
}

// ---------------- W_eff prep: dequant + rank-32 LR via one MFMA step ----------------
__global__ __launch_bounds__(256) void k_wprep(
    const unsigned short* __restrict__ BT,   // [Nw][32] bf16
    const unsigned short* __restrict__ Abf,  // [Kw][32] bf16
    const int* __restrict__ q,               // [Nw][Kw] int32
    const float* __restrict__ scale,         // [Nw]
    unsigned short* __restrict__ W,          // [Nw][Kw] bf16 out
    int Nw, int Kw)
{
    __shared__ unsigned short As[128 * 32];
    __shared__ unsigned short Bs[128 * 32];
    const int tid = threadIdx.x, wid = tid >> 6, lane = tid & 63;
    const int wr = wid >> 1, wc = wid & 1;
    const int brow = blockIdx.y * 128;   // n
    const int bcol = blockIdx.x * 128;   // k
    const int srow = wid * 16 + (lane >> 2), scol = (lane & 3) * 8;

    gload16(BT + (size_t)(brow + srow) * 32 + scol,        &As[wid * 512]);
    gload16(BT + (size_t)(brow + 64 + srow) * 32 + scol,   &As[wid * 512 + 2048]);
    gload16(Abf + (size_t)(bcol + srow) * 32 + scol,       &Bs[wid * 512]);
    gload16(Abf + (size_t)(bcol + 64 + srow) * 32 + scol,  &Bs[wid * 512 + 2048]);
    __syncthreads();

    const int fr = lane & 15, kg = (lane >> 4) * 8;
    f32x4 acc[4][4] = {};
    short8 af[4], bfr[4];
#pragma unroll
    for (int i = 0; i < 4; i++)
        af[i] = *(const short8*)&As[(wr * 64 + i * 16 + fr) * 32 + kg];
#pragma unroll
    for (int j = 0; j < 4; j++)
        bfr[j] = *(const short8*)&Bs[(wc * 64 + j * 16 + fr) * 32 + kg];
#pragma unroll
    for (int i = 0; i < 4; i++)
#pragma unroll
        for (int j = 0; j < 4; j++)
            acc[i][j] = __builtin_amdgcn_mfma_f32_16x16x32_bf16(af[i], bfr[j], acc[i][j], 0, 0, 0);

    const int q4 = lane >> 4;
#pragma unroll
    for (int i = 0; i < 4; i++) {
#pragma unroll
        for (int t = 0; t < 4; t++) {
            int n = brow + wr * 64 + i * 16 + q4 * 4 + t;
            float sc = scale[n] * 0.005f;
#pragma unroll
            for (int j = 0; j < 4; j++) {
                int k = bcol + wc * 64 + j * 16 + fr;
                size_t off = (size_t)n * Kw + k;
                float w = ((float)q[off] - 7.5f) * sc + 0.02f * acc[i][j][t];
                W[off] = f2bf(w);
            }
        }
    }
}

// ================== shared GEMM schedule machinery (R5 = best-known) ==============
// 512 threads = 8 waves (2M x 4N); per-wave C 128x64; BK=64; 8 windows/tile;
// reads for window w+1 issued pre-barrier in window w; MFMA clusters of 8;
// stage calendar P0:B0(t+1) P2:A0(t+2) P4:B1(t+2) P6:A1(t+2); cert vmcnt(2)
// at P4-top (pre-barrier, R6-safe).

#define STG(p, k0, doff) gload16((p) + (k0), smem + (doff) + ldw)
#define LDA8(dst, P, IH) { _Pragma("unroll") \
    for (int i4 = 0; i4 < 4; ++i4) dst[i4] = *(const short8*)&(P)[(IH)*8192 + i4*1024]; }
#define LDB4(dst, P, JH) { _Pragma("unroll") \
    for (int j2 = 0; j2 < 2; ++j2) dst[j2] = *(const short8*)&(P)[(JH)*8192 + j2*1024]; }
#define MF8(AF, BF, IH, JH) { __builtin_amdgcn_s_setprio(1); \
    _Pragma("unroll") for (int i4 = 0; i4 < 4; ++i4) \
    _Pragma("unroll") for (int j2 = 0; j2 < 2; ++j2) \
        acc[(IH)*4+i4][(JH)*2+j2] = __builtin_amdgcn_mfma_f32_16x16x32_bf16( \
            AF[i4], BF[j2], acc[(IH)*4+i4][(JH)*2+j2], 0, 0, 0); \
    __builtin_amdgcn_s_setprio(0); }

#define TILE(BB, t, S2, SB0, CERT, RNEXT) { \
    const int kN = ((t) + 1) << 6, kN2 = ((t) + 2) << 6; \
    LDA8(afY, aP[BB][1], 0); LDB4(bfY, bP[BB][1], 0); \
    __builtin_amdgcn_s_barrier(); \
    if (SB0) { STG(bS[0], kN, (1-(BB))*32768 + 16384); \
               STG(bS[1], kN, (1-(BB))*32768 + 20480); } \
    MF8(afX, bfX, 0, 0); \
    LDB4(bfX, bP[BB][0], 1); \
    __builtin_amdgcn_s_barrier(); \
    MF8(afY, bfY, 0, 0); \
    LDB4(bfY, bP[BB][1], 1); \
    __builtin_amdgcn_s_barrier(); \
    if (S2) { STG(aS[0], kN2, (BB)*32768); STG(aS[1], kN2, (BB)*32768 + 4096); } \
    MF8(afX, bfX, 0, 1); \
    LDA8(afX, aP[BB][0], 1); \
    __builtin_amdgcn_s_barrier(); \
    MF8(afY, bfY, 0, 1); \
    LDA8(afY, aP[BB][1], 1); \
    if (CERT == 1) asm volatile("s_waitcnt vmcnt(2)" ::: "memory"); \
    if (CERT == 2) asm volatile("s_waitcnt vmcnt(0)" ::: "memory"); \
    __builtin_amdgcn_s_barrier(); \
    if (S2) { STG(bS[2], kN2, (BB)*32768 + 24576); STG(bS[3], kN2, (BB)*32768 + 28672); } \
    MF8(afX, bfX, 1, 1); \
    LDB4(bfX, bP[BB][0], 0); \
    __builtin_amdgcn_s_barrier(); \
    MF8(afY, bfY, 1, 1); \
    LDB4(bfY, bP[BB][1], 0); \
    __builtin_amdgcn_s_barrier(); \
    if (S2) { STG(aS[2], kN2, (BB)*32768 + 8192); STG(aS[3], kN2, (BB)*32768 + 12288); } \
    MF8(afX, bfX, 1, 0); \
    if (RNEXT) { LDA8(afX, aP[1-(BB)][0], 0); LDB4(bfX, bP[1-(BB)][0], 0); } \
    __builtin_amdgcn_s_barrier(); \
    MF8(afY, bfY, 1, 0); \
}

#define GEMM_BODY(K_) { \
    const int NT = (K_) >> 6; \
    STG(aS[0], 0, 0);      STG(aS[1], 0, 4096); \
    STG(bS[0], 0, 16384);  STG(bS[1], 0, 20480); \
    STG(bS[2], 0, 24576);  STG(bS[3], 0, 28672); \
    STG(aS[2], 0, 8192);   STG(aS[3], 0, 12288); \
    STG(aS[0], 64, 32768);         STG(aS[1], 64, 32768 + 4096); \
    STG(bS[2], 64, 32768 + 24576); STG(bS[3], 64, 32768 + 28672); \
    STG(aS[2], 64, 32768 + 8192);  STG(aS[3], 64, 32768 + 12288); \
    asm volatile("s_waitcnt vmcnt(6)" ::: "memory"); \
    __builtin_amdgcn_s_barrier(); \
    LDA8(afX, aP[0][0], 0); LDB4(bfX, bP[0][0], 0); \
    int t = 0; \
    for (; t + 4 <= NT; t += 2) { \
        TILE(0, t,     1, 1, 1, 1); \
        TILE(1, t + 1, 1, 1, 1, 1); \
    } \
    TILE(0, NT - 2, 0, 1, 2, 1); \
    TILE(1, NT - 1, 0, 0, 0, 0); \
}

// ---------------- fused gate+up GEMM: h = silu(x@Wg^T) * (x@Wu^T) ----------------
// Block: 256 M-rows x 128 N-cols of BOTH g and u. B-LDS rows 0-127 = wg chunk
// (jh=0 -> g), rows 128-255 = wu chunk (jh=1 -> u), SAME output cols.
// N-MAJOR lid mapping: within an XCD chunk consecutive blocks share the same
// weight panel (resident weights ~= L2), x re-reads hit L3.
__global__ __launch_bounds__(512, 1) void k_gemmfused(
    const unsigned short* __restrict__ A,    // [M][K] bf16 (x)
    const unsigned short* __restrict__ Wg,   // [NI][K] bf16
    const unsigned short* __restrict__ Wu,   // [NI][K] bf16
    unsigned short* __restrict__ H,          // [M][NI] bf16 out
    int M, int NI, int K)
{
    extern __shared__ unsigned short smem[];   // 128 KiB
    const int tid = threadIdx.x, wid = tid >> 6, lane = tid & 63;
    const int wr = wid >> 2, wc = wid & 3;

    const int gx = NI >> 7;                    // 128-wide output tiles
    const int my = M >> 8;
    const int nwg = gx * my;
    int orig = blockIdx.y * gx + blockIdx.x;
    int q8 = nwg >> 3, r8 = nwg & 7;
    int xcd = orig & 7, lid = orig >> 3;
    int wg = (xcd < r8 ? xcd * (q8 + 1) : r8 * (q8 + 1) + (xcd - r8) * q8) + lid;
    const int bcol = (wg / my) << 7;           // N-major: consecutive wg share N-col
    const int brow = (wg % my) << 8;

    const int rg = lane >> 3;
    const int ss = ((lane & 7) ^ rg) * 8;
    const unsigned short* aS[4];
    const unsigned short* bS[4];
#pragma unroll
    for (int c = 0; c < 4; c++) {
        int arow = c * 64 + wid * 8 + rg;
        aS[c] = A + (size_t)(brow + arow) * K + ss;
    }
#pragma unroll
    for (int c = 0; c < 2; c++) {
        int nrow = c * 64 + wid * 8 + rg;      // 0..127 within the 128-chunk
        bS[c]     = Wg + (size_t)(bcol + nrow) * K + ss;
        bS[c + 2] = Wu + (size_t)(bcol + nrow) * K + ss;
    }
    const int ldw = wid * 512;

    f32x4 acc[8][4] = {};
    short8 afX[4], afY[4], bfX[2], bfY[2];
    const int fr = lane & 15, qk = lane >> 4, f7 = fr & 7;

    const unsigned short* aP[2][2];
    const unsigned short* bP[2][2];
#pragma unroll
    for (int b = 0; b < 2; ++b)
#pragma unroll
        for (int kk = 0; kk < 2; ++kk) {
            int swz = (((kk << 2) | qk) ^ f7) << 3;
            aP[b][kk] = smem + b * 32768 + (wr * 64 + fr) * 64 + swz;
            bP[b][kk] = smem + b * 32768 + 16384 + (wc * 32 + fr) * 64 + swz;
        }

    GEMM_BODY(K);

    // epilogue: acc[i][j2] = g, acc[i][2+j2] = u at the same (m, col).
    const int q4 = lane >> 4;
#pragma unroll
    for (int i = 0; i < 8; ++i) {
#pragma unroll
        for (int j2 = 0; j2 < 2; ++j2) {
#pragma unroll
            for (int tt = 0; tt < 4; ++tt) {
                int m = brow + (i >> 2) * 128 + wr * 64 + (i & 3) * 16 + q4 * 4 + tt;
                int n = bcol + wc * 32 + j2 * 16 + fr;
                float g = acc[i][j2][tt];
                float u = acc[i][2 + j2][tt];
                float s = g / (1.0f + __expf(-g));   // silu(g)
                H[(size_t)m * NI + n] = f2bf(s * u);
            }
        }
    }
}

// ---------------- down GEMM: C[M][N] = A[M][K] @ B[N][K]^T, f32 out --------------
__global__ __launch_bounds__(512, 1) void k_gemmdown(
    const unsigned short* __restrict__ A,   // [M][K] bf16 (h)
    const unsigned short* __restrict__ B,   // [N][K] bf16 (wd)
    float* __restrict__ C,                  // [M][N] f32
    int M, int N, int K)
{
    extern __shared__ unsigned short smem[];   // 128 KiB
    const int tid = threadIdx.x, wid = tid >> 6, lane = tid & 63;
    const int wr = wid >> 2, wc = wid & 3;

    const int gx = N >> 8;
    const int my = M >> 8;
    const int nwg = gx * my;
    int orig = blockIdx.y * gx + blockIdx.x;
    int q8 = nwg >> 3, r8 = nwg & 7;
    int xcd = orig & 7, lid = orig >> 3;
    int wg = (xcd < r8 ? xcd * (q8 + 1) : r8 * (q8 + 1) + (xcd - r8) * q8) + lid;
    const int bcol = (wg / my) << 8;           // N-major within chunk
    const int brow = (wg % my) << 8;

    const int rg = lane >> 3;
    const int ss = ((lane & 7) ^ rg) * 8;
    const unsigned short* aS[4];
    const unsigned short* bS[4];
#pragma unroll
    for (int c = 0; c < 4; c++) {
        int row = c * 64 + wid * 8 + rg;
        aS[c] = A + (size_t)(brow + row) * K + ss;
        bS[c] = B + (size_t)(bcol + row) * K + ss;
    }
    const int ldw = wid * 512;

    f32x4 acc[8][4] = {};
    short8 afX[4], afY[4], bfX[2], bfY[2];
    const int fr = lane & 15, qk = lane >> 4, f7 = fr & 7;

    const unsigned short* aP[2][2];
    const unsigned short* bP[2][2];
#pragma unroll
    for (int b = 0; b < 2; ++b)
#pragma unroll
        for (int kk = 0; kk < 2; ++kk) {
            int swz = (((kk << 2) | qk) ^ f7) << 3;
            aP[b][kk] = smem + b * 32768 + (wr * 64 + fr) * 64 + swz;
            bP[b][kk] = smem + b * 32768 + 16384 + (wc * 32 + fr) * 64 + swz;
        }

    GEMM_BODY(K);

    const int q4 = lane >> 4;
#pragma unroll
    for (int i = 0; i < 8; ++i) {
#pragma unroll
        for (int j = 0; j < 4; ++j) {
#pragma unroll
            for (int tt = 0; tt < 4; ++tt) {
                int m = brow + (i >> 2) * 128 + wr * 64 + (i & 3) * 16 + q4 * 4 + tt;
                int n = bcol + (j >> 1) * 128 + wc * 32 + (j & 1) * 16 + fr;
                C[(size_t)m * N + n] = acc[i][j][tt];
            }
        }
    }
}

// ---------------- host launch ----------------
extern "C" void kernel_launch(void* const* d_in, const int* in_sizes, int n_in,
                              void* d_out, int out_size, void* d_ws, size_t ws_size,
                              hipStream_t stream) {
    (void)in_sizes; (void)n_in; (void)out_size; (void)ws_size;
    const float* x          = (const float*)d_in[0];
    const int*   gate_q     = (const int*)d_in[1];
    const float* gate_scale = (const float*)d_in[2];
    const float* gate_A     = (const float*)d_in[3];
    const float* gate_B     = (const float*)d_in[4];
    const int*   up_q       = (const int*)d_in[5];
    const float* up_scale   = (const float*)d_in[6];
    const float* up_A       = (const float*)d_in[7];
    const float* up_B       = (const float*)d_in[8];
    const int*   down_q     = (const int*)d_in[9];
    const float* down_scale = (const float*)d_in[10];
    const float* down_A     = (const float*)d_in[11];
    const float* down_B     = (const float*)d_in[12];

    char* ws = (char*)d_ws;
    size_t off = 0;
    auto alloc = [&](size_t bytes) {
        void* p = ws + off; off += (bytes + 255) & ~(size_t)255; return p;
    };
    unsigned short* xbf  = (unsigned short*)alloc((size_t)M_TOK * H_DIM * 2);
    unsigned short* wgm  = (unsigned short*)alloc((size_t)I_DIM * H_DIM * 2);
    unsigned short* wum  = (unsigned short*)alloc((size_t)I_DIM * H_DIM * 2);
    unsigned short* wdm  = (unsigned short*)alloc((size_t)H_DIM * I_DIM * 2);
    unsigned short* hbuf = (unsigned short*)alloc((size_t)M_TOK * I_DIM * 2);
    unsigned short* AgBf = (unsigned short*)alloc((size_t)H_DIM * 32 * 2);
    unsigned short* AuBf = (unsigned short*)alloc((size_t)H_DIM * 32 * 2);
    unsigned short* AdBf = (unsigned short*)alloc((size_t)I_DIM * 32 * 2);
    unsigned short* BgT  = (unsigned short*)alloc((size_t)I_DIM * 32 * 2);
    unsigned short* BuT  = (unsigned short*)alloc((size_t)I_DIM * 32 * 2);
    unsigned short* BdT  = (unsigned short*)alloc((size_t)H_DIM * 32 * 2);

    (void)hipFuncSetAttribute((const void*)k_gemmfused,
        hipFuncAttributeMaxDynamicSharedMemorySize, 131072);
    (void)hipFuncSetAttribute((const void*)k_gemmdown,
        hipFuncAttributeMaxDynamicSharedMemorySize, 131072);

    // merged conversions (x, A's, B-transposes)
    k_prep_all<<<2048, 256, 0, stream>>>(x, gate_A, up_A, down_A,
                                         gate_B, up_B, down_B,
                                         xbf, AgBf, AuBf, AdBf, BgT, BuT, BdT);

    // W_eff = dequant + 0.02*(A@B)^T   (bf16)
    k_wprep<<<dim3(H_DIM / 128, I_DIM / 128), 256, 0, stream>>>(BgT, AgBf, gate_q, gate_scale, wgm, I_DIM, H_DIM);
    k_wprep<<<dim3(H_DIM / 128, I_DIM / 128), 256, 0, stream>>>(BuT, AuBf, up_q,   up_scale,   wum, I_DIM, H_DIM);
    k_wprep<<<dim3(I_DIM / 128, H_DIM / 128), 256, 0, stream>>>(BdT, AdBf, down_q, down_scale, wdm, H_DIM, I_DIM);

    // h = silu(x @ Wg^T) * (x @ Wu^T)   (fused, bf16 out)
    k_gemmfused<<<dim3(I_DIM / 128, M_TOK / 256), 512, 131072, stream>>>(
        xbf, wgm, wum, hbuf, M_TOK, I_DIM, H_DIM);
    // out = h @ Wd^T   (f32)
    k_gemmdown<<<dim3(H_DIM / 256, M_TOK / 256), 512, 131072, stream>>>(
        hbuf, wdm, (float*)d_out, M_TOK, H_DIM, I_DIM);
}

// Round 14
// 1120.788 us; speedup vs baseline: 1.8333x; 1.0035x over previous
//
#include <hip/hip_runtime.h>
#include <hip/hip_bf16.h>
#include <stdint.h>

// Problem constants
#define H_DIM 4096
#define I_DIM 11008
#define M_TOK 4096   // B*S = 2*2048

typedef __attribute__((ext_vector_type(8))) short short8;  // 8 bf16 (4 VGPRs)
typedef __attribute__((ext_vector_type(4))) float f32x4;   // 4 fp32

static __device__ __forceinline__ float bf2f(unsigned short u) {
    union { uint32_t i; float f; } v; v.i = ((uint32_t)u) << 16; return v.f;
}
static __device__ __forceinline__ unsigned short f2bf(float f) {
    union { float f; uint32_t i; } v; v.f = f;
    uint32_t r = v.i + 0x7FFF + ((v.i >> 16) & 1);   // RNE
    return (unsigned short)(r >> 16);
}

// async global->LDS, 16B per lane; LDS dest is the wave-uniform base.
static __device__ __forceinline__ void gload16(const void* g, void* l) {
    __builtin_amdgcn_global_load_lds(
        (const __attribute__((address_space(1))) void*)g,
        (__attribute__((address_space(3))) void*)l, 16, 0, 0);
}

// ---------------- merged prep kernel: all f32->bf16 conversions + B transposes ----
__global__ void k_prep_all(
    const float* __restrict__ x,
    const float* __restrict__ gA, const float* __restrict__ uA,
    const float* __restrict__ dA,
    const float* __restrict__ gB, const float* __restrict__ uB,
    const float* __restrict__ dB,
    unsigned short* __restrict__ xbf,
    unsigned short* __restrict__ AgBf, unsigned short* __restrict__ AuBf,
    unsigned short* __restrict__ AdBf,
    unsigned short* __restrict__ BgT, unsigned short* __restrict__ BuT,
    unsigned short* __restrict__ BdT)
{
    const int XN4 = (M_TOK * H_DIM) / 4;
    const int GA4 = (H_DIM * 32) / 4;
    const int DA4 = (I_DIM * 32) / 4;
    const int TOT4 = XN4 + 2 * GA4 + DA4;
    const int stride = gridDim.x * blockDim.x;
    for (int i = blockIdx.x * blockDim.x + threadIdx.x; i < TOT4; i += stride) {
        int j = i; const float* src; unsigned short* dst;
        if (j < XN4) { src = x; dst = xbf; }
        else if ((j -= XN4) < GA4) { src = gA; dst = AgBf; }
        else if ((j -= GA4) < GA4) { src = uA; dst = AuBf; }
        else { j -= GA4; src = dA; dst = AdBf; }
        f32x4 v = ((const f32x4*)src)[j];
        uint64_t p = (uint64_t)f2bf(v[0]) | ((uint64_t)f2bf(v[1]) << 16) |
                     ((uint64_t)f2bf(v[2]) << 32) | ((uint64_t)f2bf(v[3]) << 48);
        ((uint64_t*)dst)[j] = p;
    }
    const int TBI = I_DIM * 32, TBH = H_DIM * 32;
    const int TOTT = 2 * TBI + TBH;
    for (int i = blockIdx.x * blockDim.x + threadIdx.x; i < TOTT; i += stride) {
        int j = i; const float* src; unsigned short* dst; int N;
        if (j < TBI) { src = gB; dst = BgT; N = I_DIM; }
        else if ((j -= TBI) < TBI) { src = uB; dst = BuT; N = I_DIM; }
        else { j -= TBI; src = dB; dst = BdT; N = H_DIM; }
        int n = j >> 5, r = j & 31;
        dst[j] = f2bf(src[r * N + n]);
    }
}

// ---------------- W_eff prep: dequant + rank-32 LR via one MFMA step ----------------
__global__ __launch_bounds__(256) void k_wprep(
    const unsigned short* __restrict__ BT,   // [Nw][32] bf16
    const unsigned short* __restrict__ Abf,  // [Kw][32] bf16
    const int* __restrict__ q,               // [Nw][Kw] int32
    const float* __restrict__ scale,         // [Nw]
    unsigned short* __restrict__ W,          // [Nw][Kw] bf16 out
    int Nw, int Kw)
{
    __shared__ unsigned short As[128 * 32];
    __shared__ unsigned short Bs[128 * 32];
    const int tid = threadIdx.x, wid = tid >> 6, lane = tid & 63;
    const int wr = wid >> 1, wc = wid & 1;
    const int brow = blockIdx.y * 128;   // n
    const int bcol = blockIdx.x * 128;   // k
    const int srow = wid * 16 + (lane >> 2), scol = (lane & 3) * 8;

    gload16(BT + (size_t)(brow + srow) * 32 + scol,        &As[wid * 512]);
    gload16(BT + (size_t)(brow + 64 + srow) * 32 + scol,   &As[wid * 512 + 2048]);
    gload16(Abf + (size_t)(bcol + srow) * 32 + scol,       &Bs[wid * 512]);
    gload16(Abf + (size_t)(bcol + 64 + srow) * 32 + scol,  &Bs[wid * 512 + 2048]);
    __syncthreads();

    const int fr = lane & 15, kg = (lane >> 4) * 8;
    f32x4 acc[4][4] = {};
    short8 af[4], bfr[4];
#pragma unroll
    for (int i = 0; i < 4; i++)
        af[i] = *(const short8*)&As[(wr * 64 + i * 16 + fr) * 32 + kg];
#pragma unroll
    for (int j = 0; j < 4; j++)
        bfr[j] = *(const short8*)&Bs[(wc * 64 + j * 16 + fr) * 32 + kg];
#pragma unroll
    for (int i = 0; i < 4; i++)
#pragma unroll
        for (int j = 0; j < 4; j++)
            acc[i][j] = __builtin_amdgcn_mfma_f32_16x16x32_bf16(af[i], bfr[j], acc[i][j], 0, 0, 0);

    const int q4 = lane >> 4;
#pragma unroll
    for (int i = 0; i < 4; i++) {
#pragma unroll
        for (int t = 0; t < 4; t++) {
            int n = brow + wr * 64 + i * 16 + q4 * 4 + t;
            float sc = scale[n] * 0.005f;
#pragma unroll
            for (int j = 0; j < 4; j++) {
                int k = bcol + wc * 64 + j * 16 + fr;
                size_t off = (size_t)n * Kw + k;
                float w = ((float)q[off] - 7.5f) * sc + 0.02f * acc[i][j][t];
                W[off] = f2bf(w);
            }
        }
    }
}

// ================== shared GEMM schedule machinery (R5 = best-known) ==============
// 512 threads = 8 waves (2M x 4N); per-wave C 128x64; BK=64; 8 windows/tile;
// reads for window w+1 issued pre-barrier in window w; MFMA clusters of 8;
// stage calendar P0:B0(t+1) P2:A0(t+2) P4:B1(t+2) P6:A1(t+2); cert vmcnt(2)
// at P4-top (pre-barrier, R6-safe).

#define STG(p, k0, doff) gload16((p) + (k0), smem + (doff) + ldw)
#define LDA8(dst, P, IH) { _Pragma("unroll") \
    for (int i4 = 0; i4 < 4; ++i4) dst[i4] = *(const short8*)&(P)[(IH)*8192 + i4*1024]; }
#define LDB4(dst, P, JH) { _Pragma("unroll") \
    for (int j2 = 0; j2 < 2; ++j2) dst[j2] = *(const short8*)&(P)[(JH)*8192 + j2*1024]; }
#define MF8(AF, BF, IH, JH) { __builtin_amdgcn_s_setprio(1); \
    _Pragma("unroll") for (int i4 = 0; i4 < 4; ++i4) \
    _Pragma("unroll") for (int j2 = 0; j2 < 2; ++j2) \
        acc[(IH)*4+i4][(JH)*2+j2] = __builtin_amdgcn_mfma_f32_16x16x32_bf16( \
            AF[i4], BF[j2], acc[(IH)*4+i4][(JH)*2+j2], 0, 0, 0); \
    __builtin_amdgcn_s_setprio(0); }

#define TILE(BB, t, S2, SB0, CERT, RNEXT) { \
    const int kN = ((t) + 1) << 6, kN2 = ((t) + 2) << 6; \
    LDA8(afY, aP[BB][1], 0); LDB4(bfY, bP[BB][1], 0); \
    __builtin_amdgcn_s_barrier(); \
    if (SB0) { STG(bS[0], kN, (1-(BB))*32768 + 16384); \
               STG(bS[1], kN, (1-(BB))*32768 + 20480); } \
    MF8(afX, bfX, 0, 0); \
    LDB4(bfX, bP[BB][0], 1); \
    __builtin_amdgcn_s_barrier(); \
    MF8(afY, bfY, 0, 0); \
    LDB4(bfY, bP[BB][1], 1); \
    __builtin_amdgcn_s_barrier(); \
    if (S2) { STG(aS[0], kN2, (BB)*32768); STG(aS[1], kN2, (BB)*32768 + 4096); } \
    MF8(afX, bfX, 0, 1); \
    LDA8(afX, aP[BB][0], 1); \
    __builtin_amdgcn_s_barrier(); \
    MF8(afY, bfY, 0, 1); \
    LDA8(afY, aP[BB][1], 1); \
    if (CERT == 1) asm volatile("s_waitcnt vmcnt(2)" ::: "memory"); \
    if (CERT == 2) asm volatile("s_waitcnt vmcnt(0)" ::: "memory"); \
    __builtin_amdgcn_s_barrier(); \
    if (S2) { STG(bS[2], kN2, (BB)*32768 + 24576); STG(bS[3], kN2, (BB)*32768 + 28672); } \
    MF8(afX, bfX, 1, 1); \
    LDB4(bfX, bP[BB][0], 0); \
    __builtin_amdgcn_s_barrier(); \
    MF8(afY, bfY, 1, 1); \
    LDB4(bfY, bP[BB][1], 0); \
    __builtin_amdgcn_s_barrier(); \
    if (S2) { STG(aS[2], kN2, (BB)*32768 + 8192); STG(aS[3], kN2, (BB)*32768 + 12288); } \
    MF8(afX, bfX, 1, 0); \
    if (RNEXT) { LDA8(afX, aP[1-(BB)][0], 0); LDB4(bfX, bP[1-(BB)][0], 0); } \
    __builtin_amdgcn_s_barrier(); \
    MF8(afY, bfY, 1, 0); \
}

#define GEMM_BODY(K_) { \
    const int NT = (K_) >> 6; \
    STG(aS[0], 0, 0);      STG(aS[1], 0, 4096); \
    STG(bS[0], 0, 16384);  STG(bS[1], 0, 20480); \
    STG(bS[2], 0, 24576);  STG(bS[3], 0, 28672); \
    STG(aS[2], 0, 8192);   STG(aS[3], 0, 12288); \
    STG(aS[0], 64, 32768);         STG(aS[1], 64, 32768 + 4096); \
    STG(bS[2], 64, 32768 + 24576); STG(bS[3], 64, 32768 + 28672); \
    STG(aS[2], 64, 32768 + 8192);  STG(aS[3], 64, 32768 + 12288); \
    asm volatile("s_waitcnt vmcnt(6)" ::: "memory"); \
    __builtin_amdgcn_s_barrier(); \
    LDA8(afX, aP[0][0], 0); LDB4(bfX, bP[0][0], 0); \
    int t = 0; \
    for (; t + 4 <= NT; t += 2) { \
        TILE(0, t,     1, 1, 1, 1); \
        TILE(1, t + 1, 1, 1, 1, 1); \
    } \
    TILE(0, NT - 2, 0, 1, 2, 1); \
    TILE(1, NT - 1, 0, 0, 0, 0); \
}

// ---------------- fused gate+up GEMM: h = silu(x@Wg^T) * (x@Wu^T) ----------------
// Block: 256 M-rows x 128 N-cols of BOTH g and u. B-LDS rows 0-127 = wg chunk
// (jh=0 -> g), rows 128-255 = wu chunk (jh=1 -> u), SAME output cols.
// M-major lid mapping (R12-proven; N-major remap regressed, R13).
__global__ __launch_bounds__(512, 1) void k_gemmfused(
    const unsigned short* __restrict__ A,    // [M][K] bf16 (x)
    const unsigned short* __restrict__ Wg,   // [NI][K] bf16
    const unsigned short* __restrict__ Wu,   // [NI][K] bf16
    unsigned short* __restrict__ H,          // [M][NI] bf16 out
    int M, int NI, int K)
{
    extern __shared__ unsigned short smem[];   // 128 KiB
    const int tid = threadIdx.x, wid = tid >> 6, lane = tid & 63;
    const int wr = wid >> 2, wc = wid & 3;

    const int gx = NI >> 7;                    // 128-wide output tiles
    const int nwg = gx * (M >> 8);
    int orig = blockIdx.y * gx + blockIdx.x;
    int q8 = nwg >> 3, r8 = nwg & 7;
    int xcd = orig & 7, lid = orig >> 3;
    int wg = (xcd < r8 ? xcd * (q8 + 1) : r8 * (q8 + 1) + (xcd - r8) * q8) + lid;
    const int bcol = (wg % gx) << 7;
    const int brow = (wg / gx) << 8;

    const int rg = lane >> 3;
    const int ss = ((lane & 7) ^ rg) * 8;
    const unsigned short* aS[4];
    const unsigned short* bS[4];
#pragma unroll
    for (int c = 0; c < 4; c++) {
        int arow = c * 64 + wid * 8 + rg;
        aS[c] = A + (size_t)(brow + arow) * K + ss;
    }
#pragma unroll
    for (int c = 0; c < 2; c++) {
        int nrow = c * 64 + wid * 8 + rg;      // 0..127 within the 128-chunk
        bS[c]     = Wg + (size_t)(bcol + nrow) * K + ss;
        bS[c + 2] = Wu + (size_t)(bcol + nrow) * K + ss;
    }
    const int ldw = wid * 512;

    f32x4 acc[8][4] = {};
    short8 afX[4], afY[4], bfX[2], bfY[2];
    const int fr = lane & 15, qk = lane >> 4, f7 = fr & 7;

    const unsigned short* aP[2][2];
    const unsigned short* bP[2][2];
#pragma unroll
    for (int b = 0; b < 2; ++b)
#pragma unroll
        for (int kk = 0; kk < 2; ++kk) {
            int swz = (((kk << 2) | qk) ^ f7) << 3;
            aP[b][kk] = smem + b * 32768 + (wr * 64 + fr) * 64 + swz;
            bP[b][kk] = smem + b * 32768 + 16384 + (wc * 32 + fr) * 64 + swz;
        }

    GEMM_BODY(K);

    // epilogue: acc[i][j2] = g, acc[i][2+j2] = u at the same (m, col).
    const int q4 = lane >> 4;
#pragma unroll
    for (int i = 0; i < 8; ++i) {
#pragma unroll
        for (int j2 = 0; j2 < 2; ++j2) {
#pragma unroll
            for (int tt = 0; tt < 4; ++tt) {
                int m = brow + (i >> 2) * 128 + wr * 64 + (i & 3) * 16 + q4 * 4 + tt;
                int n = bcol + wc * 32 + j2 * 16 + fr;
                float g = acc[i][j2][tt];
                float u = acc[i][2 + j2][tt];
                float s = g / (1.0f + __expf(-g));   // silu(g)
                H[(size_t)m * NI + n] = f2bf(s * u);
            }
        }
    }
}

// ---------------- down GEMM: C[M][N] = A[M][K] @ B[N][K]^T, f32 out --------------
__global__ __launch_bounds__(512, 1) void k_gemmdown(
    const unsigned short* __restrict__ A,   // [M][K] bf16 (h)
    const unsigned short* __restrict__ B,   // [N][K] bf16 (wd)
    float* __restrict__ C,                  // [M][N] f32
    int M, int N, int K)
{
    extern __shared__ unsigned short smem[];   // 128 KiB
    const int tid = threadIdx.x, wid = tid >> 6, lane = tid & 63;
    const int wr = wid >> 2, wc = wid & 3;

    const int gx = N >> 8;
    const int nwg = gx * (M >> 8);
    int orig = blockIdx.y * gx + blockIdx.x;
    int q8 = nwg >> 3, r8 = nwg & 7;
    int xcd = orig & 7, lid = orig >> 3;
    int wg = (xcd < r8 ? xcd * (q8 + 1) : r8 * (q8 + 1) + (xcd - r8) * q8) + lid;
    const int bcol = (wg % gx) << 8;
    const int brow = (wg / gx) << 8;

    const int rg = lane >> 3;
    const int ss = ((lane & 7) ^ rg) * 8;
    const unsigned short* aS[4];
    const unsigned short* bS[4];
#pragma unroll
    for (int c = 0; c < 4; c++) {
        int row = c * 64 + wid * 8 + rg;
        aS[c] = A + (size_t)(brow + row) * K + ss;
        bS[c] = B + (size_t)(bcol + row) * K + ss;
    }
    const int ldw = wid * 512;

    f32x4 acc[8][4] = {};
    short8 afX[4], afY[4], bfX[2], bfY[2];
    const int fr = lane & 15, qk = lane >> 4, f7 = fr & 7;

    const unsigned short* aP[2][2];
    const unsigned short* bP[2][2];
#pragma unroll
    for (int b = 0; b < 2; ++b)
#pragma unroll
        for (int kk = 0; kk < 2; ++kk) {
            int swz = (((kk << 2) | qk) ^ f7) << 3;
            aP[b][kk] = smem + b * 32768 + (wr * 64 + fr) * 64 + swz;
            bP[b][kk] = smem + b * 32768 + 16384 + (wc * 32 + fr) * 64 + swz;
        }

    GEMM_BODY(K);

    const int q4 = lane >> 4;
#pragma unroll
    for (int i = 0; i < 8; ++i) {
#pragma unroll
        for (int j = 0; j < 4; ++j) {
#pragma unroll
            for (int tt = 0; tt < 4; ++tt) {
                int m = brow + (i >> 2) * 128 + wr * 64 + (i & 3) * 16 + q4 * 4 + tt;
                int n = bcol + (j >> 1) * 128 + wc * 32 + (j & 1) * 16 + fr;
                C[(size_t)m * N + n] = acc[i][j][tt];
            }
        }
    }
}

// ---------------- host launch ----------------
extern "C" void kernel_launch(void* const* d_in, const int* in_sizes, int n_in,
                              void* d_out, int out_size, void* d_ws, size_t ws_size,
                              hipStream_t stream) {
    (void)in_sizes; (void)n_in; (void)out_size; (void)ws_size;
    const float* x          = (const float*)d_in[0];
    const int*   gate_q     = (const int*)d_in[1];
    const float* gate_scale = (const float*)d_in[2];
    const float* gate_A     = (const float*)d_in[3];
    const float* gate_B     = (const float*)d_in[4];
    const int*   up_q       = (const int*)d_in[5];
    const float* up_scale   = (const float*)d_in[6];
    const float* up_A       = (const float*)d_in[7];
    const float* up_B       = (const float*)d_in[8];
    const int*   down_q     = (const int*)d_in[9];
    const float* down_scale = (const float*)d_in[10];
    const float* down_A     = (const float*)d_in[11];
    const float* down_B     = (const float*)d_in[12];

    char* ws = (char*)d_ws;
    size_t off = 0;
    auto alloc = [&](size_t bytes) {
        void* p = ws + off; off += (bytes + 255) & ~(size_t)255; return p;
    };
    unsigned short* xbf  = (unsigned short*)alloc((size_t)M_TOK * H_DIM * 2);
    unsigned short* wgm  = (unsigned short*)alloc((size_t)I_DIM * H_DIM * 2);
    unsigned short* wum  = (unsigned short*)alloc((size_t)I_DIM * H_DIM * 2);
    unsigned short* wdm  = (unsigned short*)alloc((size_t)H_DIM * I_DIM * 2);
    unsigned short* hbuf = (unsigned short*)alloc((size_t)M_TOK * I_DIM * 2);
    unsigned short* AgBf = (unsigned short*)alloc((size_t)H_DIM * 32 * 2);
    unsigned short* AuBf = (unsigned short*)alloc((size_t)H_DIM * 32 * 2);
    unsigned short* AdBf = (unsigned short*)alloc((size_t)I_DIM * 32 * 2);
    unsigned short* BgT  = (unsigned short*)alloc((size_t)I_DIM * 32 * 2);
    unsigned short* BuT  = (unsigned short*)alloc((size_t)I_DIM * 32 * 2);
    unsigned short* BdT  = (unsigned short*)alloc((size_t)H_DIM * 32 * 2);

    (void)hipFuncSetAttribute((const void*)k_gemmfused,
        hipFuncAttributeMaxDynamicSharedMemorySize, 131072);
    (void)hipFuncSetAttribute((const void*)k_gemmdown,
        hipFuncAttributeMaxDynamicSharedMemorySize, 131072);

    // merged conversions (x, A's, B-transposes)
    k_prep_all<<<2048, 256, 0, stream>>>(x, gate_A, up_A, down_A,
                                         gate_B, up_B, down_B,
                                         xbf, AgBf, AuBf, AdBf, BgT, BuT, BdT);

    // W_eff = dequant + 0.02*(A@B)^T   (bf16)
    k_wprep<<<dim3(H_DIM / 128, I_DIM / 128), 256, 0, stream>>>(BgT, AgBf, gate_q, gate_scale, wgm, I_DIM, H_DIM);
    k_wprep<<<dim3(H_DIM / 128, I_DIM / 128), 256, 0, stream>>>(BuT, AuBf, up_q,   up_scale,   wum, I_DIM, H_DIM);
    k_wprep<<<dim3(I_DIM / 128, H_DIM / 128), 256, 0, stream>>>(BdT, AdBf, down_q, down_scale, wdm, H_DIM, I_DIM);

    // h = silu(x @ Wg^T) * (x @ Wu^T)   (fused, bf16 out)
    k_gemmfused<<<dim3(I_DIM / 128, M_TOK / 256), 512, 131072, stream>>>(
        xbf, wgm, wum, hbuf, M_TOK, I_DIM, H_DIM);
    // out = h @ Wd^T   (f32)
    k_gemmdown<<<dim3(H_DIM / 256, M_TOK / 256), 512, 131072, stream>>>(
        hbuf, wdm, (float*)d_out, M_TOK, H_DIM, I_DIM);
}

// Round 15
// 1111.806 us; speedup vs baseline: 1.8481x; 1.0081x over previous
//
#include <hip/hip_runtime.h>
#include <hip/hip_bf16.h>
#include <stdint.h>

// Problem constants
#define H_DIM 4096
#define I_DIM 11008
#define M_TOK 4096   // B*S = 2*2048

typedef __attribute__((ext_vector_type(8))) short short8;  // 8 bf16 (4 VGPRs)
typedef __attribute__((ext_vector_type(4))) float f32x4;   // 4 fp32

static __device__ __forceinline__ float bf2f(unsigned short u) {
    union { uint32_t i; float f; } v; v.i = ((uint32_t)u) << 16; return v.f;
}
static __device__ __forceinline__ unsigned short f2bf(float f) {
    union { float f; uint32_t i; } v; v.f = f;
    uint32_t r = v.i + 0x7FFF + ((v.i >> 16) & 1);   // RNE
    return (unsigned short)(r >> 16);
}

// async global->LDS, 16B per lane; LDS dest is the wave-uniform base.
static __device__ __forceinline__ void gload16(const void* g, void* l) {
    __builtin_amdgcn_global_load_lds(
        (const __attribute__((address_space(1))) void*)g,
        (__attribute__((address_space(3))) void*)l, 16, 0, 0);
}

// ---------------- merged prep kernel: all f32->bf16 conversions + B transposes ----
__global__ void k_prep_all(
    const float* __restrict__ x,
    const float* __restrict__ gA, const float* __restrict__ uA,
    const float* __restrict__ dA,
    const float* __restrict__ gB, const float* __restrict__ uB,
    const float* __restrict__ dB,
    unsigned short* __restrict__ xbf,
    unsigned short* __restrict__ AgBf, unsigned short* __restrict__ AuBf,
    unsigned short* __restrict__ AdBf,
    unsigned short* __restrict__ BgT, unsigned short* __restrict__ BuT,
    unsigned short* __restrict__ BdT)
{
    const int XN4 = (M_TOK * H_DIM) / 4;
    const int GA4 = (H_DIM * 32) / 4;
    const int DA4 = (I_DIM * 32) / 4;
    const int TOT4 = XN4 + 2 * GA4 + DA4;
    const int stride = gridDim.x * blockDim.x;
    for (int i = blockIdx.x * blockDim.x + threadIdx.x; i < TOT4; i += stride) {
        int j = i; const float* src; unsigned short* dst;
        if (j < XN4) { src = x; dst = xbf; }
        else if ((j -= XN4) < GA4) { src = gA; dst = AgBf; }
        else if ((j -= GA4) < GA4) { src = uA; dst = AuBf; }
        else { j -= GA4; src = dA; dst = AdBf; }
        f32x4 v = ((const f32x4*)src)[j];
        uint64_t p = (uint64_t)f2bf(v[0]) | ((uint64_t)f2bf(v[1]) << 16) |
                     ((uint64_t)f2bf(v[2]) << 32) | ((uint64_t)f2bf(v[3]) << 48);
        ((uint64_t*)dst)[j] = p;
    }
    const int TBI = I_DIM * 32, TBH = H_DIM * 32;
    const int TOTT = 2 * TBI + TBH;
    for (int i = blockIdx.x * blockDim.x + threadIdx.x; i < TOTT; i += stride) {
        int j = i; const float* src; unsigned short* dst; int N;
        if (j < TBI) { src = gB; dst = BgT; N = I_DIM; }
        else if ((j -= TBI) < TBI) { src = uB; dst = BuT; N = I_DIM; }
        else { j -= TBI; src = dB; dst = BdT; N = H_DIM; }
        int n = j >> 5, r = j & 31;
        dst[j] = f2bf(src[r * N + n]);
    }
}

// ---------------- merged W_eff prep (gate+up+down in ONE dispatch) ----------------
// W[n][k] = (q[n][k]-7.5)*scale[n]*0.005 + 0.02 * sum_r BT[n][r]*Abf[k][r]
// gate/up: Nw=I (86 row-tiles), Kw=H (32 col-tiles); down: Nw=H (32), Kw=I (86).
// Each problem = 2752 blocks; flattened 1D grid of 3*2752 removes the two
// kernel-boundary drains between the three BW-bound dispatches.
__global__ __launch_bounds__(256) void k_wprep3(
    const unsigned short* __restrict__ BTg, const unsigned short* __restrict__ Ag,
    const int* __restrict__ qg, const float* __restrict__ sg,
    unsigned short* __restrict__ Wgo,
    const unsigned short* __restrict__ BTu, const unsigned short* __restrict__ Au,
    const int* __restrict__ qu, const float* __restrict__ su,
    unsigned short* __restrict__ Wuo,
    const unsigned short* __restrict__ BTd, const unsigned short* __restrict__ Ad,
    const int* __restrict__ qd, const float* __restrict__ sd,
    unsigned short* __restrict__ Wdo)
{
    const int b = blockIdx.x;
    const int which = b / 2752;          // 0 gate, 1 up, 2 down
    const int lb = b - which * 2752;
    const unsigned short *BT, *Abf; const int* q; const float* scale;
    unsigned short* W; int Nw, Kw, bx, by;
    if (which == 0) { BT = BTg; Abf = Ag; q = qg; scale = sg; W = Wgo;
                      Nw = I_DIM; Kw = H_DIM; bx = lb & 31; by = lb >> 5; }
    else if (which == 1) { BT = BTu; Abf = Au; q = qu; scale = su; W = Wuo;
                      Nw = I_DIM; Kw = H_DIM; bx = lb & 31; by = lb >> 5; }
    else { BT = BTd; Abf = Ad; q = qd; scale = sd; W = Wdo;
           Nw = H_DIM; Kw = I_DIM; bx = lb % 86; by = lb / 86; }
    (void)Nw;

    __shared__ unsigned short As[128 * 32];
    __shared__ unsigned short Bs[128 * 32];
    const int tid = threadIdx.x, wid = tid >> 6, lane = tid & 63;
    const int wr = wid >> 1, wc = wid & 1;
    const int brow = by * 128;   // n
    const int bcol = bx * 128;   // k
    const int srow = wid * 16 + (lane >> 2), scol = (lane & 3) * 8;

    gload16(BT + (size_t)(brow + srow) * 32 + scol,        &As[wid * 512]);
    gload16(BT + (size_t)(brow + 64 + srow) * 32 + scol,   &As[wid * 512 + 2048]);
    gload16(Abf + (size_t)(bcol + srow) * 32 + scol,       &Bs[wid * 512]);
    gload16(Abf + (size_t)(bcol + 64 + srow) * 32 + scol,  &Bs[wid * 512 + 2048]);
    __syncthreads();

    const int fr = lane & 15, kg = (lane >> 4) * 8;
    f32x4 acc[4][4] = {};
    short8 af[4], bfr[4];
#pragma unroll
    for (int i = 0; i < 4; i++)
        af[i] = *(const short8*)&As[(wr * 64 + i * 16 + fr) * 32 + kg];
#pragma unroll
    for (int j = 0; j < 4; j++)
        bfr[j] = *(const short8*)&Bs[(wc * 64 + j * 16 + fr) * 32 + kg];
#pragma unroll
    for (int i = 0; i < 4; i++)
#pragma unroll
        for (int j = 0; j < 4; j++)
            acc[i][j] = __builtin_amdgcn_mfma_f32_16x16x32_bf16(af[i], bfr[j], acc[i][j], 0, 0, 0);

    const int q4 = lane >> 4;
#pragma unroll
    for (int i = 0; i < 4; i++) {
#pragma unroll
        for (int t = 0; t < 4; t++) {
            int n = brow + wr * 64 + i * 16 + q4 * 4 + t;
            float sc = scale[n] * 0.005f;
#pragma unroll
            for (int j = 0; j < 4; j++) {
                int k = bcol + wc * 64 + j * 16 + fr;
                size_t off = (size_t)n * Kw + k;
                float w = ((float)q[off] - 7.5f) * sc + 0.02f * acc[i][j][t];
                W[off] = f2bf(w);
            }
        }
    }
}

// ================== shared GEMM schedule machinery (R5 = best-known) ==============
// 512 threads = 8 waves (2M x 4N); per-wave C 128x64; BK=64; 8 windows/tile;
// reads for window w+1 issued pre-barrier in window w; MFMA clusters of 8;
// stage calendar P0:B0(t+1) P2:A0(t+2) P4:B1(t+2) P6:A1(t+2); cert vmcnt(2)
// at P4-top (pre-barrier, R6-safe).

#define STG(p, k0, doff) gload16((p) + (k0), smem + (doff) + ldw)
#define LDA8(dst, P, IH) { _Pragma("unroll") \
    for (int i4 = 0; i4 < 4; ++i4) dst[i4] = *(const short8*)&(P)[(IH)*8192 + i4*1024]; }
#define LDB4(dst, P, JH) { _Pragma("unroll") \
    for (int j2 = 0; j2 < 2; ++j2) dst[j2] = *(const short8*)&(P)[(JH)*8192 + j2*1024]; }
#define MF8(AF, BF, IH, JH) { __builtin_amdgcn_s_setprio(1); \
    _Pragma("unroll") for (int i4 = 0; i4 < 4; ++i4) \
    _Pragma("unroll") for (int j2 = 0; j2 < 2; ++j2) \
        acc[(IH)*4+i4][(JH)*2+j2] = __builtin_amdgcn_mfma_f32_16x16x32_bf16( \
            AF[i4], BF[j2], acc[(IH)*4+i4][(JH)*2+j2], 0, 0, 0); \
    __builtin_amdgcn_s_setprio(0); }

#define TILE(BB, t, S2, SB0, CERT, RNEXT) { \
    const int kN = ((t) + 1) << 6, kN2 = ((t) + 2) << 6; \
    LDA8(afY, aP[BB][1], 0); LDB4(bfY, bP[BB][1], 0); \
    __builtin_amdgcn_s_barrier(); \
    if (SB0) { STG(bS[0], kN, (1-(BB))*32768 + 16384); \
               STG(bS[1], kN, (1-(BB))*32768 + 20480); } \
    MF8(afX, bfX, 0, 0); \
    LDB4(bfX, bP[BB][0], 1); \
    __builtin_amdgcn_s_barrier(); \
    MF8(afY, bfY, 0, 0); \
    LDB4(bfY, bP[BB][1], 1); \
    __builtin_amdgcn_s_barrier(); \
    if (S2) { STG(aS[0], kN2, (BB)*32768); STG(aS[1], kN2, (BB)*32768 + 4096); } \
    MF8(afX, bfX, 0, 1); \
    LDA8(afX, aP[BB][0], 1); \
    __builtin_amdgcn_s_barrier(); \
    MF8(afY, bfY, 0, 1); \
    LDA8(afY, aP[BB][1], 1); \
    if (CERT == 1) asm volatile("s_waitcnt vmcnt(2)" ::: "memory"); \
    if (CERT == 2) asm volatile("s_waitcnt vmcnt(0)" ::: "memory"); \
    __builtin_amdgcn_s_barrier(); \
    if (S2) { STG(bS[2], kN2, (BB)*32768 + 24576); STG(bS[3], kN2, (BB)*32768 + 28672); } \
    MF8(afX, bfX, 1, 1); \
    LDB4(bfX, bP[BB][0], 0); \
    __builtin_amdgcn_s_barrier(); \
    MF8(afY, bfY, 1, 1); \
    LDB4(bfY, bP[BB][1], 0); \
    __builtin_amdgcn_s_barrier(); \
    if (S2) { STG(aS[2], kN2, (BB)*32768 + 8192); STG(aS[3], kN2, (BB)*32768 + 12288); } \
    MF8(afX, bfX, 1, 0); \
    if (RNEXT) { LDA8(afX, aP[1-(BB)][0], 0); LDB4(bfX, bP[1-(BB)][0], 0); } \
    __builtin_amdgcn_s_barrier(); \
    MF8(afY, bfY, 1, 0); \
}

#define GEMM_BODY(K_) { \
    const int NT = (K_) >> 6; \
    STG(aS[0], 0, 0);      STG(aS[1], 0, 4096); \
    STG(bS[0], 0, 16384);  STG(bS[1], 0, 20480); \
    STG(bS[2], 0, 24576);  STG(bS[3], 0, 28672); \
    STG(aS[2], 0, 8192);   STG(aS[3], 0, 12288); \
    STG(aS[0], 64, 32768);         STG(aS[1], 64, 32768 + 4096); \
    STG(bS[2], 64, 32768 + 24576); STG(bS[3], 64, 32768 + 28672); \
    STG(aS[2], 64, 32768 + 8192);  STG(aS[3], 64, 32768 + 12288); \
    asm volatile("s_waitcnt vmcnt(6)" ::: "memory"); \
    __builtin_amdgcn_s_barrier(); \
    LDA8(afX, aP[0][0], 0); LDB4(bfX, bP[0][0], 0); \
    int t = 0; \
    for (; t + 4 <= NT; t += 2) { \
        TILE(0, t,     1, 1, 1, 1); \
        TILE(1, t + 1, 1, 1, 1, 1); \
    } \
    TILE(0, NT - 2, 0, 1, 2, 1); \
    TILE(1, NT - 1, 0, 0, 0, 0); \
}

// ---------------- fused gate+up GEMM: h = silu(x@Wg^T) * (x@Wu^T) ----------------
// Block: 256 M-rows x 128 N-cols of BOTH g and u. B-LDS rows 0-127 = wg chunk
// (jh=0 -> g), rows 128-255 = wu chunk (jh=1 -> u), SAME output cols.
// M-major lid mapping (R12-proven; N-major remap regressed, R13).
__global__ __launch_bounds__(512, 1) void k_gemmfused(
    const unsigned short* __restrict__ A,    // [M][K] bf16 (x)
    const unsigned short* __restrict__ Wg,   // [NI][K] bf16
    const unsigned short* __restrict__ Wu,   // [NI][K] bf16
    unsigned short* __restrict__ H,          // [M][NI] bf16 out
    int M, int NI, int K)
{
    extern __shared__ unsigned short smem[];   // 128 KiB
    const int tid = threadIdx.x, wid = tid >> 6, lane = tid & 63;
    const int wr = wid >> 2, wc = wid & 3;

    const int gx = NI >> 7;                    // 128-wide output tiles
    const int nwg = gx * (M >> 8);
    int orig = blockIdx.y * gx + blockIdx.x;
    int q8 = nwg >> 3, r8 = nwg & 7;
    int xcd = orig & 7, lid = orig >> 3;
    int wg = (xcd < r8 ? xcd * (q8 + 1) : r8 * (q8 + 1) + (xcd - r8) * q8) + lid;
    const int bcol = (wg % gx) << 7;
    const int brow = (wg / gx) << 8;

    const int rg = lane >> 3;
    const int ss = ((lane & 7) ^ rg) * 8;
    const unsigned short* aS[4];
    const unsigned short* bS[4];
#pragma unroll
    for (int c = 0; c < 4; c++) {
        int arow = c * 64 + wid * 8 + rg;
        aS[c] = A + (size_t)(brow + arow) * K + ss;
    }
#pragma unroll
    for (int c = 0; c < 2; c++) {
        int nrow = c * 64 + wid * 8 + rg;      // 0..127 within the 128-chunk
        bS[c]     = Wg + (size_t)(bcol + nrow) * K + ss;
        bS[c + 2] = Wu + (size_t)(bcol + nrow) * K + ss;
    }
    const int ldw = wid * 512;

    f32x4 acc[8][4] = {};
    short8 afX[4], afY[4], bfX[2], bfY[2];
    const int fr = lane & 15, qk = lane >> 4, f7 = fr & 7;

    const unsigned short* aP[2][2];
    const unsigned short* bP[2][2];
#pragma unroll
    for (int b = 0; b < 2; ++b)
#pragma unroll
        for (int kk = 0; kk < 2; ++kk) {
            int swz = (((kk << 2) | qk) ^ f7) << 3;
            aP[b][kk] = smem + b * 32768 + (wr * 64 + fr) * 64 + swz;
            bP[b][kk] = smem + b * 32768 + 16384 + (wc * 32 + fr) * 64 + swz;
        }

    GEMM_BODY(K);

    // epilogue: acc[i][j2] = g, acc[i][2+j2] = u at the same (m, col).
    const int q4 = lane >> 4;
#pragma unroll
    for (int i = 0; i < 8; ++i) {
#pragma unroll
        for (int j2 = 0; j2 < 2; ++j2) {
#pragma unroll
            for (int tt = 0; tt < 4; ++tt) {
                int m = brow + (i >> 2) * 128 + wr * 64 + (i & 3) * 16 + q4 * 4 + tt;
                int n = bcol + wc * 32 + j2 * 16 + fr;
                float g = acc[i][j2][tt];
                float u = acc[i][2 + j2][tt];
                float s = g / (1.0f + __expf(-g));   // silu(g)
                H[(size_t)m * NI + n] = f2bf(s * u);
            }
        }
    }
}

// ---------------- down GEMM: C[M][N] = A[M][K] @ B[N][K]^T, f32 out --------------
__global__ __launch_bounds__(512, 1) void k_gemmdown(
    const unsigned short* __restrict__ A,   // [M][K] bf16 (h)
    const unsigned short* __restrict__ B,   // [N][K] bf16 (wd)
    float* __restrict__ C,                  // [M][N] f32
    int M, int N, int K)
{
    extern __shared__ unsigned short smem[];   // 128 KiB
    const int tid = threadIdx.x, wid = tid >> 6, lane = tid & 63;
    const int wr = wid >> 2, wc = wid & 3;

    const int gx = N >> 8;
    const int nwg = gx * (M >> 8);
    int orig = blockIdx.y * gx + blockIdx.x;
    int q8 = nwg >> 3, r8 = nwg & 7;
    int xcd = orig & 7, lid = orig >> 3;
    int wg = (xcd < r8 ? xcd * (q8 + 1) : r8 * (q8 + 1) + (xcd - r8) * q8) + lid;
    const int bcol = (wg % gx) << 8;
    const int brow = (wg / gx) << 8;

    const int rg = lane >> 3;
    const int ss = ((lane & 7) ^ rg) * 8;
    const unsigned short* aS[4];
    const unsigned short* bS[4];
#pragma unroll
    for (int c = 0; c < 4; c++) {
        int row = c * 64 + wid * 8 + rg;
        aS[c] = A + (size_t)(brow + row) * K + ss;
        bS[c] = B + (size_t)(bcol + row) * K + ss;
    }
    const int ldw = wid * 512;

    f32x4 acc[8][4] = {};
    short8 afX[4], afY[4], bfX[2], bfY[2];
    const int fr = lane & 15, qk = lane >> 4, f7 = fr & 7;

    const unsigned short* aP[2][2];
    const unsigned short* bP[2][2];
#pragma unroll
    for (int b = 0; b < 2; ++b)
#pragma unroll
        for (int kk = 0; kk < 2; ++kk) {
            int swz = (((kk << 2) | qk) ^ f7) << 3;
            aP[b][kk] = smem + b * 32768 + (wr * 64 + fr) * 64 + swz;
            bP[b][kk] = smem + b * 32768 + 16384 + (wc * 32 + fr) * 64 + swz;
        }

    GEMM_BODY(K);

    const int q4 = lane >> 4;
#pragma unroll
    for (int i = 0; i < 8; ++i) {
#pragma unroll
        for (int j = 0; j < 4; ++j) {
#pragma unroll
            for (int tt = 0; tt < 4; ++tt) {
                int m = brow + (i >> 2) * 128 + wr * 64 + (i & 3) * 16 + q4 * 4 + tt;
                int n = bcol + (j >> 1) * 128 + wc * 32 + (j & 1) * 16 + fr;
                C[(size_t)m * N + n] = acc[i][j][tt];
            }
        }
    }
}

// ---------------- host launch ----------------
extern "C" void kernel_launch(void* const* d_in, const int* in_sizes, int n_in,
                              void* d_out, int out_size, void* d_ws, size_t ws_size,
                              hipStream_t stream) {
    (void)in_sizes; (void)n_in; (void)out_size; (void)ws_size;
    const float* x          = (const float*)d_in[0];
    const int*   gate_q     = (const int*)d_in[1];
    const float* gate_scale = (const float*)d_in[2];
    const float* gate_A     = (const float*)d_in[3];
    const float* gate_B     = (const float*)d_in[4];
    const int*   up_q       = (const int*)d_in[5];
    const float* up_scale   = (const float*)d_in[6];
    const float* up_A       = (const float*)d_in[7];
    const float* up_B       = (const float*)d_in[8];
    const int*   down_q     = (const int*)d_in[9];
    const float* down_scale = (const float*)d_in[10];
    const float* down_A     = (const float*)d_in[11];
    const float* down_B     = (const float*)d_in[12];

    char* ws = (char*)d_ws;
    size_t off = 0;
    auto alloc = [&](size_t bytes) {
        void* p = ws + off; off += (bytes + 255) & ~(size_t)255; return p;
    };
    unsigned short* xbf  = (unsigned short*)alloc((size_t)M_TOK * H_DIM * 2);
    unsigned short* wgm  = (unsigned short*)alloc((size_t)I_DIM * H_DIM * 2);
    unsigned short* wum  = (unsigned short*)alloc((size_t)I_DIM * H_DIM * 2);
    unsigned short* wdm  = (unsigned short*)alloc((size_t)H_DIM * I_DIM * 2);
    unsigned short* hbuf = (unsigned short*)alloc((size_t)M_TOK * I_DIM * 2);
    unsigned short* AgBf = (unsigned short*)alloc((size_t)H_DIM * 32 * 2);
    unsigned short* AuBf = (unsigned short*)alloc((size_t)H_DIM * 32 * 2);
    unsigned short* AdBf = (unsigned short*)alloc((size_t)I_DIM * 32 * 2);
    unsigned short* BgT  = (unsigned short*)alloc((size_t)I_DIM * 32 * 2);
    unsigned short* BuT  = (unsigned short*)alloc((size_t)I_DIM * 32 * 2);
    unsigned short* BdT  = (unsigned short*)alloc((size_t)H_DIM * 32 * 2);

    (void)hipFuncSetAttribute((const void*)k_gemmfused,
        hipFuncAttributeMaxDynamicSharedMemorySize, 131072);
    (void)hipFuncSetAttribute((const void*)k_gemmdown,
        hipFuncAttributeMaxDynamicSharedMemorySize, 131072);

    // merged conversions (x, A's, B-transposes)
    k_prep_all<<<2048, 256, 0, stream>>>(x, gate_A, up_A, down_A,
                                         gate_B, up_B, down_B,
                                         xbf, AgBf, AuBf, AdBf, BgT, BuT, BdT);

    // W_eff = dequant + 0.02*(A@B)^T for gate+up+down in ONE dispatch
    k_wprep3<<<3 * 2752, 256, 0, stream>>>(
        BgT, AgBf, gate_q, gate_scale, wgm,
        BuT, AuBf, up_q,   up_scale,   wum,
        BdT, AdBf, down_q, down_scale, wdm);

    // h = silu(x @ Wg^T) * (x @ Wu^T)   (fused, bf16 out)
    k_gemmfused<<<dim3(I_DIM / 128, M_TOK / 256), 512, 131072, stream>>>(
        xbf, wgm, wum, hbuf, M_TOK, I_DIM, H_DIM);
    // out = h @ Wd^T   (f32)
    k_gemmdown<<<dim3(H_DIM / 256, M_TOK / 256), 512, 131072, stream>>>(
        hbuf, wdm, (float*)d_out, M_TOK, H_DIM, I_DIM);
}

// Round 17
// 910.126 us; speedup vs baseline: 2.2576x; 1.2216x over previous
//
#include <hip/hip_runtime.h>
#include <hip/hip_bf16.h>
#include <stdint.h>

// Problem constants
#define H_DIM 4096
#define I_DIM 11008
#define M_TOK 4096   // B*S = 2*2048

typedef __attribute__((ext_vector_type(8))) short short8;  // 8 bf16 (4 VGPRs)
typedef __attribute__((ext_vector_type(4))) float f32x4;   // 4 fp32
typedef __attribute__((ext_vector_type(4))) int   i32x4;   // 4 i32 (i8-MFMA operand/acc)

#define SX_DIV 6.0f   // x i8 scale: xi = round(x * 127/6)
#define QS (0.0025f * SX_DIV / 127.0f)   // dequant: acc * s_n * QS

static __device__ __forceinline__ float bf2f(unsigned short u) {
    union { uint32_t i; float f; } v; v.i = ((uint32_t)u) << 16; return v.f;
}
static __device__ __forceinline__ unsigned short f2bf(float f) {
    union { float f; uint32_t i; } v; v.f = f;
    uint32_t r = v.i + 0x7FFF + ((v.i >> 16) & 1);   // RNE
    return (unsigned short)(r >> 16);
}

// async global->LDS, 16B per lane; LDS dest is the wave-uniform base.
static __device__ __forceinline__ void gload16(const void* g, void* l) {
    __builtin_amdgcn_global_load_lds(
        (const __attribute__((address_space(1))) void*)g,
        (__attribute__((address_space(3))) void*)l, 16, 0, 0);
}

// ---------------- prep: conversions, transposes, x->i8, q->i8 ---------------------
__global__ void k_prep_all(
    const float* __restrict__ x,
    const int* __restrict__ gq, const int* __restrict__ uq,
    const float* __restrict__ gA, const float* __restrict__ uA,
    const float* __restrict__ dA,
    const float* __restrict__ gB, const float* __restrict__ uB,
    const float* __restrict__ dB,
    unsigned short* __restrict__ xbf, char* __restrict__ xi8,
    char* __restrict__ Wg8, char* __restrict__ Wu8,
    unsigned short* __restrict__ AgT, unsigned short* __restrict__ AuT,
    unsigned short* __restrict__ AdBf,
    unsigned short* __restrict__ BgT, unsigned short* __restrict__ BuT,
    unsigned short* __restrict__ BdT)
{
    const int stride = gridDim.x * blockDim.x;
    const int tid0 = blockIdx.x * blockDim.x + threadIdx.x;
    // S1: x -> xbf (bf16) + xi8 (i8, fixed scale)
    const int XN4 = (M_TOK * H_DIM) / 4;
    const float SXI = 127.0f / SX_DIV;
    for (int i = tid0; i < XN4; i += stride) {
        f32x4 v = ((const f32x4*)x)[i];
        uint64_t p = (uint64_t)f2bf(v[0]) | ((uint64_t)f2bf(v[1]) << 16) |
                     ((uint64_t)f2bf(v[2]) << 32) | ((uint64_t)f2bf(v[3]) << 48);
        ((uint64_t*)xbf)[i] = p;
        uint32_t q8 = 0;
#pragma unroll
        for (int t = 0; t < 4; t++) {
            int a = (int)lrintf(v[t] * SXI);
            a = a > 127 ? 127 : (a < -127 ? -127 : a);
            q8 |= ((uint32_t)(a & 255)) << (8 * t);
        }
        ((uint32_t*)xi8)[i] = q8;
    }
    // S2: gate/up q (int32 0..15) -> i8 (2q-15)
    const int QN4 = (I_DIM * H_DIM) / 4;
    for (int i = tid0; i < 2 * QN4; i += stride) {
        int j = i; const int* src; char* dst;
        if (j < QN4) { src = gq; dst = Wg8; } else { j -= QN4; src = uq; dst = Wu8; }
        i32x4 qv = ((const i32x4*)src)[j];
        uint32_t p = 0;
#pragma unroll
        for (int t = 0; t < 4; t++)
            p |= ((uint32_t)((2 * qv[t] - 15) & 255)) << (8 * t);
        ((uint32_t*)dst)[j] = p;
    }
    // S3: AgT/AuT [32][H] bf16 (transposed) + AdBf [I][32] bf16 (linear)
    const int AT = 32 * H_DIM;
    for (int i = tid0; i < 2 * AT; i += stride) {
        int j = i; const float* src; unsigned short* dst;
        if (j < AT) { src = gA; dst = AgT; } else { j -= AT; src = uA; dst = AuT; }
        int r = j >> 12, k = j & 4095;
        dst[j] = f2bf(src[k * 32 + r]);
    }
    const int AD = I_DIM * 32;
    for (int i = tid0; i < AD; i += stride) AdBf[i] = f2bf(dA[i]);
    // S4: B transposes -> [N][32] bf16
    const int TBI = I_DIM * 32, TBH = H_DIM * 32;
    for (int i = tid0; i < 2 * TBI + TBH; i += stride) {
        int j = i; const float* src; unsigned short* dst; int N;
        if (j < TBI) { src = gB; dst = BgT; N = I_DIM; }
        else if ((j -= TBI) < TBI) { src = uB; dst = BuT; N = I_DIM; }
        else { j -= TBI; src = dB; dst = BdT; N = H_DIM; }
        int n = j >> 5, r = j & 31;
        dst[j] = f2bf(src[r * N + n]);
    }
}

// ---------------- T = 0.02 * (x @ A): skinny M x 32 GEMM, bf16 out ---------------
__global__ __launch_bounds__(256) void k_T(
    const unsigned short* __restrict__ xbf,  // [M][H] bf16
    const unsigned short* __restrict__ AgT,  // [32][H] bf16
    const unsigned short* __restrict__ AuT,
    unsigned short* __restrict__ Tg,         // [M][32] bf16
    unsigned short* __restrict__ Tu)
{
    const unsigned short* AT = blockIdx.y ? AuT : AgT;
    unsigned short* T = blockIdx.y ? Tu : Tg;
    const int wid = threadIdx.x >> 6, lane = threadIdx.x & 63;
    const int base = blockIdx.x * 64 + wid * 16;
    const int l15 = lane & 15, kg = (lane >> 4) * 8;
    f32x4 acc0 = {}, acc1 = {};
    for (int k0 = 0; k0 < H_DIM; k0 += 32) {
        short8 af = *(const short8*)&xbf[(size_t)(base + l15) * H_DIM + k0 + kg];
        short8 b0 = *(const short8*)&AT[(size_t)l15 * H_DIM + k0 + kg];
        short8 b1 = *(const short8*)&AT[(size_t)(16 + l15) * H_DIM + k0 + kg];
        acc0 = __builtin_amdgcn_mfma_f32_16x16x32_bf16(af, b0, acc0, 0, 0, 0);
        acc1 = __builtin_amdgcn_mfma_f32_16x16x32_bf16(af, b1, acc1, 0, 0, 0);
    }
    const int q4 = lane >> 4;
#pragma unroll
    for (int t = 0; t < 4; t++) {
        int m = base + q4 * 4 + t;
        T[m * 32 + l15]      = f2bf(acc0[t] * 0.02f);
        T[m * 32 + 16 + l15] = f2bf(acc1[t] * 0.02f);
    }
}

// ---------------- W_eff prep for DOWN only (dequant + LR fold, bf16) --------------
__global__ __launch_bounds__(256) void k_wprep(
    const unsigned short* __restrict__ BT,   // [Nw][32] bf16
    const unsigned short* __restrict__ Abf,  // [Kw][32] bf16
    const int* __restrict__ q,               // [Nw][Kw] int32
    const float* __restrict__ scale,         // [Nw]
    unsigned short* __restrict__ W,          // [Nw][Kw] bf16 out
    int Nw, int Kw)
{
    __shared__ unsigned short As[128 * 32];
    __shared__ unsigned short Bs[128 * 32];
    const int tid = threadIdx.x, wid = tid >> 6, lane = tid & 63;
    const int wr = wid >> 1, wc = wid & 1;
    const int brow = blockIdx.y * 128;
    const int bcol = blockIdx.x * 128;
    const int srow = wid * 16 + (lane >> 2), scol = (lane & 3) * 8;

    gload16(BT + (size_t)(brow + srow) * 32 + scol,        &As[wid * 512]);
    gload16(BT + (size_t)(brow + 64 + srow) * 32 + scol,   &As[wid * 512 + 2048]);
    gload16(Abf + (size_t)(bcol + srow) * 32 + scol,       &Bs[wid * 512]);
    gload16(Abf + (size_t)(bcol + 64 + srow) * 32 + scol,  &Bs[wid * 512 + 2048]);
    __syncthreads();

    const int fr = lane & 15, kg = (lane >> 4) * 8;
    f32x4 acc[4][4] = {};
    short8 af[4], bfr[4];
#pragma unroll
    for (int i = 0; i < 4; i++)
        af[i] = *(const short8*)&As[(wr * 64 + i * 16 + fr) * 32 + kg];
#pragma unroll
    for (int j = 0; j < 4; j++)
        bfr[j] = *(const short8*)&Bs[(wc * 64 + j * 16 + fr) * 32 + kg];
#pragma unroll
    for (int i = 0; i < 4; i++)
#pragma unroll
        for (int j = 0; j < 4; j++)
            acc[i][j] = __builtin_amdgcn_mfma_f32_16x16x32_bf16(af[i], bfr[j], acc[i][j], 0, 0, 0);

    const int q4 = lane >> 4;
#pragma unroll
    for (int i = 0; i < 4; i++) {
#pragma unroll
        for (int t = 0; t < 4; t++) {
            int n = brow + wr * 64 + i * 16 + q4 * 4 + t;
            float sc = scale[n] * 0.005f;
#pragma unroll
            for (int j = 0; j < 4; j++) {
                int k = bcol + wc * 64 + j * 16 + fr;
                size_t off = (size_t)n * Kw + k;
                float w = ((float)q[off] - 7.5f) * sc + 0.02f * acc[i][j][t];
                W[off] = f2bf(w);
            }
        }
    }
}

// =============== fused gate+up i8 GEMM (4-window halved-R5 schedule) ===============
// h = silu(deq(x_i8@Wg8^T) + Tg@BgT^T) * (deq(x_i8@Wu8^T) + Tu@BuT^T)
// Block: 256 M x 128 N. LDS/buf: A 256x64 i8 (16K: A0 0..8K, A1 8..16K),
// Bg 128x64 (16384), Bu (24576); 2 bufs = 64KB. i8 frag: lane l: row l&15,
// k=(l>>4)*16+[0..16) (16B contiguous) -> wave covers full 1KB region/frag =
// conflict-free, linear staging (no swizzle).
// Windows: w0 MFMA(A0,Bg) rd(Bu); w1 MFMA(A0,Bu) rd(A1) stg(A0,Bg of t+2);
// w2 MFMA(A1,Bu) cert stg(Bu); w3 MFMA(A1,Bg) rd(A0',Bg') stg(A1).
// Each window: reads; barrier; stages; MFMA. Cert vmcnt(2) pre-barrier at w2
// (R6-safe: per-wave vmcnt + barrier = block-wide before w3's next-buf reads).
__global__ __launch_bounds__(512, 1) void k_gemmfu8(
    const char* __restrict__ Xq,             // [M][K] i8
    const char* __restrict__ Wg8,            // [NI][K] i8
    const char* __restrict__ Wu8,
    const unsigned short* __restrict__ Tg,   // [M][32] bf16 (0.02 folded)
    const unsigned short* __restrict__ Tu,
    const unsigned short* __restrict__ BgT,  // [NI][32] bf16
    const unsigned short* __restrict__ BuT,
    const float* __restrict__ gs, const float* __restrict__ us,
    unsigned short* __restrict__ H,          // [M][NI] bf16
    int M, int NI, int K)
{
    extern __shared__ char dynsmem[];
    char* smem = dynsmem;   // 64 KiB
    const int tid = threadIdx.x, wid = tid >> 6, lane = tid & 63;
    const int wr = wid >> 2, wc = wid & 3;

    // T1: bijective XCD swizzle, M-major (R12-proven)
    const int gx = NI >> 7;
    const int nwg = gx * (M >> 8);
    int orig = blockIdx.y * gx + blockIdx.x;
    int q8 = nwg >> 3, r8 = nwg & 7;
    int xcd = orig & 7, lid = orig >> 3;
    int wg = (xcd < r8 ? xcd * (q8 + 1) : r8 * (q8 + 1) + (xcd - r8) * q8) + lid;
    const int bcol = (wg % gx) << 7;
    const int brow = (wg / gx) << 8;

    // staging sources: line = 128 rows x 64B; thread t: row t>>2, col (t&3)*16
    const int srow = wid * 16 + (lane >> 2), scolB = (lane & 3) * 16;
    const char* aSrc  = Xq  + (size_t)(brow + srow) * K + scolB;
    const char* bgSrc = Wg8 + (size_t)(bcol + srow) * K + scolB;
    const char* buSrc = Wu8 + (size_t)(bcol + srow) * K + scolB;
    const int ldwB = wid * 1024;

    i32x4 acc[8][4];
#pragma unroll
    for (int i = 0; i < 8; ++i)
#pragma unroll
        for (int j = 0; j < 4; ++j) acc[i][j] = (i32x4){0, 0, 0, 0};

    i32x4 A0f[4], A1f[4], BgAf[2], BgBf[2], Buf[2];
    const int l15 = lane & 15, q4b = lane >> 4;
    const char* aRd = smem + (wr * 64 + l15) * 64 + q4b * 16;
    const char* bRd = smem + 16384 + (wc * 32 + l15) * 64 + q4b * 16;
    const int NT = K >> 6;   // 64

#define SA0(BB, k0) gload16(aSrc + (k0), smem + (BB)*32768 + ldwB)
#define SA1(BB, k0) gload16(aSrc + 128*(size_t)K + (k0), smem + (BB)*32768 + 8192 + ldwB)
#define SBG(BB, k0) gload16(bgSrc + (k0), smem + (BB)*32768 + 16384 + ldwB)
#define SBU(BB, k0) gload16(buSrc + (k0), smem + (BB)*32768 + 24576 + ldwB)
#define LDA0(BB) { _Pragma("unroll") for (int i4 = 0; i4 < 4; ++i4) \
    A0f[i4] = *(const i32x4*)(aRd + (BB)*32768 + i4*1024); }
#define LDA1(BB) { _Pragma("unroll") for (int i4 = 0; i4 < 4; ++i4) \
    A1f[i4] = *(const i32x4*)(aRd + (BB)*32768 + 8192 + i4*1024); }
#define LDBG(SET, BB) { _Pragma("unroll") for (int j2 = 0; j2 < 2; ++j2) \
    SET[j2] = *(const i32x4*)(bRd + (BB)*32768 + j2*1024); }
#define LDBU(BB) { _Pragma("unroll") for (int j2 = 0; j2 < 2; ++j2) \
    Buf[j2] = *(const i32x4*)(bRd + (BB)*32768 + 8192 + j2*1024); }
#define MFI(AF, BF, IH, JB) { __builtin_amdgcn_s_setprio(1); \
    _Pragma("unroll") for (int i4 = 0; i4 < 4; ++i4) \
    _Pragma("unroll") for (int j2 = 0; j2 < 2; ++j2) \
        acc[(IH)*4+i4][(JB)*2+j2] = __builtin_amdgcn_mfma_i32_16x16x64_i8( \
            AF[i4], BF[j2], acc[(IH)*4+i4][(JB)*2+j2], 0, 0, 0); \
    __builtin_amdgcn_s_setprio(0); }
#define BARR() __builtin_amdgcn_s_barrier()

// One K-tile. BGC: this tile's Bg reg set; BGN: next tile's.
// S2: stage tile t+2 (k2). CERT: 0 none / 1 vmcnt(2) / 2 vmcnt(0). RN: next reads.
#define FTILE(BB, BGC, BGN, k2, S2, CERT, RN) { \
    LDBU(BB); \
    BARR(); \
    MFI(A0f, BGC, 0, 0); \
    LDA1(BB); \
    BARR(); \
    if (S2) { SA0(BB, k2); SBG(BB, k2); } \
    MFI(A0f, Buf, 0, 1); \
    if (CERT == 1) asm volatile("s_waitcnt vmcnt(2)" ::: "memory"); \
    if (CERT == 2) asm volatile("s_waitcnt vmcnt(0)" ::: "memory"); \
    BARR(); \
    if (S2) { SBU(BB, k2); } \
    MFI(A1f, Buf, 1, 1); \
    if (RN) { LDA0(1-(BB)); LDBG(BGN, 1-(BB)); } \
    BARR(); \
    if (S2) { SA1(BB, k2); } \
    MFI(A1f, BGC, 1, 0); \
}

    // prologue: stage tiles 0 and 1 (8 lines); wait tile 0; read its A0/Bg.
    SA0(0, 0); SBG(0, 0); SBU(0, 0); SA1(0, 0);
    SA0(1, 64); SBG(1, 64); SBU(1, 64); SA1(1, 64);
    asm volatile("s_waitcnt vmcnt(4)" ::: "memory");
    BARR();
    LDA0(0); LDBG(BgAf, 0);

    for (int u = 0; u < (NT - 2) / 2; ++u) {
        const int k2a = (2 * u + 2) << 6, k2b = (2 * u + 3) << 6;
        FTILE(0, BgAf, BgBf, k2a, 1, 1, 1);
        FTILE(1, BgBf, BgAf, k2b, 1, 1, 1);
    }
    FTILE(0, BgAf, BgBf, 0, 0, 2, 1);   // tile NT-2
    FTILE(1, BgBf, BgAf, 0, 0, 0, 0);   // tile NT-1

#undef FTILE
#undef BARR
#undef MFI
#undef LDBU
#undef LDBG
#undef LDA1
#undef LDA0
#undef SBU
#undef SBG
#undef SA1
#undef SA0

    // ---- epilogue: LR correction via bf16 MFMA, silu, store ----
    __builtin_amdgcn_s_barrier();   // all K-loop LDS reads complete block-wide
    {
        const int scolH = (lane & 3) * 8;   // bf16 elems (16B)
        gload16(Tg + (size_t)(brow + srow) * 32 + scolH,        smem + ldwB);
        gload16(Tg + (size_t)(brow + 128 + srow) * 32 + scolH,  smem + 8192 + ldwB);
        gload16(Tu + (size_t)(brow + srow) * 32 + scolH,        smem + 16384 + ldwB);
        gload16(Tu + (size_t)(brow + 128 + srow) * 32 + scolH,  smem + 24576 + ldwB);
        gload16(BgT + (size_t)(bcol + srow) * 32 + scolH,       smem + 32768 + ldwB);
        gload16(BuT + (size_t)(bcol + srow) * 32 + scolH,       smem + 40960 + ldwB);
    }
    asm volatile("s_waitcnt vmcnt(0)" ::: "memory");
    __builtin_amdgcn_s_barrier();

    const int fr = l15;
    short8 BgF[2], BuF[2];
#pragma unroll
    for (int j2 = 0; j2 < 2; ++j2) {
        BgF[j2] = *(const short8*)(smem + 32768 + (wc * 32 + j2 * 16 + l15) * 64 + q4b * 16);
        BuF[j2] = *(const short8*)(smem + 40960 + (wc * 32 + j2 * 16 + l15) * 64 + q4b * 16);
    }
    float cg[2], cu[2];
#pragma unroll
    for (int j2 = 0; j2 < 2; ++j2) {
        int n = bcol + wc * 32 + j2 * 16 + fr;
        cg[j2] = gs[n] * QS;
        cu[j2] = us[n] * QS;
    }
    const int q4 = lane >> 4;
#pragma unroll
    for (int i = 0; i < 8; ++i) {
        int trow = (i >> 2) * 128 + wr * 64 + (i & 3) * 16 + l15;
        short8 tgf = *(const short8*)(smem + trow * 64 + q4b * 16);
        short8 tuf = *(const short8*)(smem + 16384 + trow * 64 + q4b * 16);
#pragma unroll
        for (int j2 = 0; j2 < 2; ++j2) {
            f32x4 ag, au;
#pragma unroll
            for (int t = 0; t < 4; ++t) {
                ag[t] = (float)acc[i][j2][t] * cg[j2];
                au[t] = (float)acc[i][2 + j2][t] * cu[j2];
            }
            ag = __builtin_amdgcn_mfma_f32_16x16x32_bf16(tgf, BgF[j2], ag, 0, 0, 0);
            au = __builtin_amdgcn_mfma_f32_16x16x32_bf16(tuf, BuF[j2], au, 0, 0, 0);
#pragma unroll
            for (int t = 0; t < 4; ++t) {
                int m = brow + (i >> 2) * 128 + wr * 64 + (i & 3) * 16 + q4 * 4 + t;
                int n = bcol + wc * 32 + j2 * 16 + fr;
                float g = ag[t];
                float s = g / (1.0f + __expf(-g));
                H[(size_t)m * NI + n] = f2bf(s * au[t]);
            }
        }
    }
}

// ================== bf16 GEMM machinery (R5 schedule) for DOWN ====================
#define STG(p, k0, doff) gload16((p) + (k0), smem + (doff) + ldw)
#define LDA8(dst, P, IH) { _Pragma("unroll") \
    for (int i4 = 0; i4 < 4; ++i4) dst[i4] = *(const short8*)&(P)[(IH)*8192 + i4*1024]; }
#define LDB4(dst, P, JH) { _Pragma("unroll") \
    for (int j2 = 0; j2 < 2; ++j2) dst[j2] = *(const short8*)&(P)[(JH)*8192 + j2*1024]; }
#define MF8(AF, BF, IH, JH) { __builtin_amdgcn_s_setprio(1); \
    _Pragma("unroll") for (int i4 = 0; i4 < 4; ++i4) \
    _Pragma("unroll") for (int j2 = 0; j2 < 2; ++j2) \
        acc[(IH)*4+i4][(JH)*2+j2] = __builtin_amdgcn_mfma_f32_16x16x32_bf16( \
            AF[i4], BF[j2], acc[(IH)*4+i4][(JH)*2+j2], 0, 0, 0); \
    __builtin_amdgcn_s_setprio(0); }

#define TILE(BB, t, S2, SB0, CERT, RNEXT) { \
    const int kN = ((t) + 1) << 6, kN2 = ((t) + 2) << 6; \
    LDA8(afY, aP[BB][1], 0); LDB4(bfY, bP[BB][1], 0); \
    __builtin_amdgcn_s_barrier(); \
    if (SB0) { STG(bS[0], kN, (1-(BB))*32768 + 16384); \
               STG(bS[1], kN, (1-(BB))*32768 + 20480); } \
    MF8(afX, bfX, 0, 0); \
    LDB4(bfX, bP[BB][0], 1); \
    __builtin_amdgcn_s_barrier(); \
    MF8(afY, bfY, 0, 0); \
    LDB4(bfY, bP[BB][1], 1); \
    __builtin_amdgcn_s_barrier(); \
    if (S2) { STG(aS[0], kN2, (BB)*32768); STG(aS[1], kN2, (BB)*32768 + 4096); } \
    MF8(afX, bfX, 0, 1); \
    LDA8(afX, aP[BB][0], 1); \
    __builtin_amdgcn_s_barrier(); \
    MF8(afY, bfY, 0, 1); \
    LDA8(afY, aP[BB][1], 1); \
    if (CERT == 1) asm volatile("s_waitcnt vmcnt(2)" ::: "memory"); \
    if (CERT == 2) asm volatile("s_waitcnt vmcnt(0)" ::: "memory"); \
    __builtin_amdgcn_s_barrier(); \
    if (S2) { STG(bS[2], kN2, (BB)*32768 + 24576); STG(bS[3], kN2, (BB)*32768 + 28672); } \
    MF8(afX, bfX, 1, 1); \
    LDB4(bfX, bP[BB][0], 0); \
    __builtin_amdgcn_s_barrier(); \
    MF8(afY, bfY, 1, 1); \
    LDB4(bfY, bP[BB][1], 0); \
    __builtin_amdgcn_s_barrier(); \
    if (S2) { STG(aS[2], kN2, (BB)*32768 + 8192); STG(aS[3], kN2, (BB)*32768 + 12288); } \
    MF8(afX, bfX, 1, 0); \
    if (RNEXT) { LDA8(afX, aP[1-(BB)][0], 0); LDB4(bfX, bP[1-(BB)][0], 0); } \
    __builtin_amdgcn_s_barrier(); \
    MF8(afY, bfY, 1, 0); \
}

#define GEMM_BODY(K_) { \
    const int NT = (K_) >> 6; \
    STG(aS[0], 0, 0);      STG(aS[1], 0, 4096); \
    STG(bS[0], 0, 16384);  STG(bS[1], 0, 20480); \
    STG(bS[2], 0, 24576);  STG(bS[3], 0, 28672); \
    STG(aS[2], 0, 8192);   STG(aS[3], 0, 12288); \
    STG(aS[0], 64, 32768);         STG(aS[1], 64, 32768 + 4096); \
    STG(bS[2], 64, 32768 + 24576); STG(bS[3], 64, 32768 + 28672); \
    STG(aS[2], 64, 32768 + 8192);  STG(aS[3], 64, 32768 + 12288); \
    asm volatile("s_waitcnt vmcnt(6)" ::: "memory"); \
    __builtin_amdgcn_s_barrier(); \
    LDA8(afX, aP[0][0], 0); LDB4(bfX, bP[0][0], 0); \
    int t = 0; \
    for (; t + 4 <= NT; t += 2) { \
        TILE(0, t,     1, 1, 1, 1); \
        TILE(1, t + 1, 1, 1, 1, 1); \
    } \
    TILE(0, NT - 2, 0, 1, 2, 1); \
    TILE(1, NT - 1, 0, 0, 0, 0); \
}

// ---------------- down GEMM: C[M][N] = A[M][K] @ B[N][K]^T, f32 out --------------
__global__ __launch_bounds__(512, 1) void k_gemmdown(
    const unsigned short* __restrict__ A,   // [M][K] bf16 (h)
    const unsigned short* __restrict__ B,   // [N][K] bf16 (wd)
    float* __restrict__ C,                  // [M][N] f32
    int M, int N, int K)
{
    extern __shared__ char dynsmem[];
    unsigned short* smem = (unsigned short*)dynsmem;   // 128 KiB
    const int tid = threadIdx.x, wid = tid >> 6, lane = tid & 63;
    const int wr = wid >> 2, wc = wid & 3;

    const int gx = N >> 8;
    const int nwg = gx * (M >> 8);
    int orig = blockIdx.y * gx + blockIdx.x;
    int q8 = nwg >> 3, r8 = nwg & 7;
    int xcd = orig & 7, lid = orig >> 3;
    int wg = (xcd < r8 ? xcd * (q8 + 1) : r8 * (q8 + 1) + (xcd - r8) * q8) + lid;
    const int bcol = (wg % gx) << 8;
    const int brow = (wg / gx) << 8;

    const int rg = lane >> 3;
    const int ss = ((lane & 7) ^ rg) * 8;
    const unsigned short* aS[4];
    const unsigned short* bS[4];
#pragma unroll
    for (int c = 0; c < 4; c++) {
        int row = c * 64 + wid * 8 + rg;
        aS[c] = A + (size_t)(brow + row) * K + ss;
        bS[c] = B + (size_t)(bcol + row) * K + ss;
    }
    const int ldw = wid * 512;

    f32x4 acc[8][4] = {};
    short8 afX[4], afY[4], bfX[2], bfY[2];
    const int fr = lane & 15, qk = lane >> 4, f7 = fr & 7;

    const unsigned short* aP[2][2];
    const unsigned short* bP[2][2];
#pragma unroll
    for (int b = 0; b < 2; ++b)
#pragma unroll
        for (int kk = 0; kk < 2; ++kk) {
            int swz = (((kk << 2) | qk) ^ f7) << 3;
            aP[b][kk] = smem + b * 32768 + (wr * 64 + fr) * 64 + swz;
            bP[b][kk] = smem + b * 32768 + 16384 + (wc * 32 + fr) * 64 + swz;
        }

    GEMM_BODY(K);

    const int q4 = lane >> 4;
#pragma unroll
    for (int i = 0; i < 8; ++i) {
#pragma unroll
        for (int j = 0; j < 4; ++j) {
#pragma unroll
            for (int tt = 0; tt < 4; ++tt) {
                int m = brow + (i >> 2) * 128 + wr * 64 + (i & 3) * 16 + q4 * 4 + tt;
                int n = bcol + (j >> 1) * 128 + wc * 32 + (j & 1) * 16 + fr;
                C[(size_t)m * N + n] = acc[i][j][tt];
            }
        }
    }
}

// ---------------- host launch ----------------
extern "C" void kernel_launch(void* const* d_in, const int* in_sizes, int n_in,
                              void* d_out, int out_size, void* d_ws, size_t ws_size,
                              hipStream_t stream) {
    (void)in_sizes; (void)n_in; (void)out_size; (void)ws_size;
    const float* x          = (const float*)d_in[0];
    const int*   gate_q     = (const int*)d_in[1];
    const float* gate_scale = (const float*)d_in[2];
    const float* gate_A     = (const float*)d_in[3];
    const float* gate_B     = (const float*)d_in[4];
    const int*   up_q       = (const int*)d_in[5];
    const float* up_scale   = (const float*)d_in[6];
    const float* up_A       = (const float*)d_in[7];
    const float* up_B       = (const float*)d_in[8];
    const int*   down_q     = (const int*)d_in[9];
    const float* down_scale = (const float*)d_in[10];
    const float* down_A     = (const float*)d_in[11];
    const float* down_B     = (const float*)d_in[12];

    char* ws = (char*)d_ws;
    size_t off = 0;
    auto alloc = [&](size_t bytes) {
        void* p = ws + off; off += (bytes + 255) & ~(size_t)255; return p;
    };
    unsigned short* xbf  = (unsigned short*)alloc((size_t)M_TOK * H_DIM * 2);
    char*           xi8  = (char*)alloc((size_t)M_TOK * H_DIM);
    char*           Wg8  = (char*)alloc((size_t)I_DIM * H_DIM);
    char*           Wu8  = (char*)alloc((size_t)I_DIM * H_DIM);
    unsigned short* wdm  = (unsigned short*)alloc((size_t)H_DIM * I_DIM * 2);
    unsigned short* hbuf = (unsigned short*)alloc((size_t)M_TOK * I_DIM * 2);
    unsigned short* Tg   = (unsigned short*)alloc((size_t)M_TOK * 32 * 2);
    unsigned short* Tu   = (unsigned short*)alloc((size_t)M_TOK * 32 * 2);
    unsigned short* AgT  = (unsigned short*)alloc((size_t)32 * H_DIM * 2);
    unsigned short* AuT  = (unsigned short*)alloc((size_t)32 * H_DIM * 2);
    unsigned short* AdBf = (unsigned short*)alloc((size_t)I_DIM * 32 * 2);
    unsigned short* BgT  = (unsigned short*)alloc((size_t)I_DIM * 32 * 2);
    unsigned short* BuT  = (unsigned short*)alloc((size_t)I_DIM * 32 * 2);
    unsigned short* BdT  = (unsigned short*)alloc((size_t)H_DIM * 32 * 2);

    (void)hipFuncSetAttribute((const void*)k_gemmfu8,
        hipFuncAttributeMaxDynamicSharedMemorySize, 65536);
    (void)hipFuncSetAttribute((const void*)k_gemmdown,
        hipFuncAttributeMaxDynamicSharedMemorySize, 131072);

    k_prep_all<<<2048, 256, 0, stream>>>(x, gate_q, up_q, gate_A, up_A, down_A,
                                         gate_B, up_B, down_B,
                                         xbf, xi8, Wg8, Wu8, AgT, AuT, AdBf,
                                         BgT, BuT, BdT);

    // Tg/Tu = 0.02 * (x @ A)
    k_T<<<dim3(M_TOK / 64, 2), 256, 0, stream>>>(xbf, AgT, AuT, Tg, Tu);

    // down W_eff (bf16, LR folded)
    k_wprep<<<dim3(I_DIM / 128, H_DIM / 128), 256, 0, stream>>>(
        BdT, AdBf, down_q, down_scale, wdm, H_DIM, I_DIM);

    // fused gate+up in i8 + LR epilogue -> h (bf16)
    k_gemmfu8<<<dim3(I_DIM / 128, M_TOK / 256), 512, 65536, stream>>>(
        xi8, Wg8, Wu8, Tg, Tu, BgT, BuT, gate_scale, up_scale,
        hbuf, M_TOK, I_DIM, H_DIM);

    // out = h @ Wd^T (f32)
    k_gemmdown<<<dim3(H_DIM / 256, M_TOK / 256), 512, 131072, stream>>>(
        hbuf, wdm, (float*)d_out, M_TOK, H_DIM, I_DIM);
}

// Round 18
// 898.017 us; speedup vs baseline: 2.2881x; 1.0135x over previous
//
#include <hip/hip_runtime.h>
#include <hip/hip_bf16.h>
#include <stdint.h>

// Problem constants
#define H_DIM 4096
#define I_DIM 11008
#define M_TOK 4096   // B*S = 2*2048

typedef __attribute__((ext_vector_type(8))) short short8;  // 8 bf16 (4 VGPRs)
typedef __attribute__((ext_vector_type(4))) float f32x4;   // 4 fp32
typedef __attribute__((ext_vector_type(4))) int   i32x4;   // 4 i32 (i8-MFMA operand/acc)

#define SX_DIV 6.0f   // x i8 scale: xi = round(x * 127/6)
#define QS (0.0025f * SX_DIV / 127.0f)   // dequant: acc * s_n * QS

static __device__ __forceinline__ float bf2f(unsigned short u) {
    union { uint32_t i; float f; } v; v.i = ((uint32_t)u) << 16; return v.f;
}
static __device__ __forceinline__ unsigned short f2bf(float f) {
    union { float f; uint32_t i; } v; v.f = f;
    uint32_t r = v.i + 0x7FFF + ((v.i >> 16) & 1);   // RNE
    return (unsigned short)(r >> 16);
}

// async global->LDS, 16B per lane; LDS dest is the wave-uniform base.
static __device__ __forceinline__ void gload16(const void* g, void* l) {
    __builtin_amdgcn_global_load_lds(
        (const __attribute__((address_space(1))) void*)g,
        (__attribute__((address_space(3))) void*)l, 16, 0, 0);
}

// ---------------- prep: conversions, transposes, x->i8, q->i8 ---------------------
__global__ void k_prep_all(
    const float* __restrict__ x,
    const int* __restrict__ gq, const int* __restrict__ uq,
    const float* __restrict__ gA, const float* __restrict__ uA,
    const float* __restrict__ dA,
    const float* __restrict__ gB, const float* __restrict__ uB,
    const float* __restrict__ dB,
    unsigned short* __restrict__ xbf, char* __restrict__ xi8,
    char* __restrict__ Wg8, char* __restrict__ Wu8,
    unsigned short* __restrict__ AgT, unsigned short* __restrict__ AuT,
    unsigned short* __restrict__ AdBf,
    unsigned short* __restrict__ BgT, unsigned short* __restrict__ BuT,
    unsigned short* __restrict__ BdT)
{
    const int stride = gridDim.x * blockDim.x;
    const int tid0 = blockIdx.x * blockDim.x + threadIdx.x;
    // S1: x -> xbf (bf16) + xi8 (i8, fixed scale)
    const int XN4 = (M_TOK * H_DIM) / 4;
    const float SXI = 127.0f / SX_DIV;
    for (int i = tid0; i < XN4; i += stride) {
        f32x4 v = ((const f32x4*)x)[i];
        uint64_t p = (uint64_t)f2bf(v[0]) | ((uint64_t)f2bf(v[1]) << 16) |
                     ((uint64_t)f2bf(v[2]) << 32) | ((uint64_t)f2bf(v[3]) << 48);
        ((uint64_t*)xbf)[i] = p;
        uint32_t q8 = 0;
#pragma unroll
        for (int t = 0; t < 4; t++) {
            int a = (int)lrintf(v[t] * SXI);
            a = a > 127 ? 127 : (a < -127 ? -127 : a);
            q8 |= ((uint32_t)(a & 255)) << (8 * t);
        }
        ((uint32_t*)xi8)[i] = q8;
    }
    // S2: gate/up q (int32 0..15) -> i8 (2q-15)
    const int QN4 = (I_DIM * H_DIM) / 4;
    for (int i = tid0; i < 2 * QN4; i += stride) {
        int j = i; const int* src; char* dst;
        if (j < QN4) { src = gq; dst = Wg8; } else { j -= QN4; src = uq; dst = Wu8; }
        i32x4 qv = ((const i32x4*)src)[j];
        uint32_t p = 0;
#pragma unroll
        for (int t = 0; t < 4; t++)
            p |= ((uint32_t)((2 * qv[t] - 15) & 255)) << (8 * t);
        ((uint32_t*)dst)[j] = p;
    }
    // S3: AgT/AuT [32][H] bf16 (transposed) + AdBf [I][32] bf16 (linear)
    const int AT = 32 * H_DIM;
    for (int i = tid0; i < 2 * AT; i += stride) {
        int j = i; const float* src; unsigned short* dst;
        if (j < AT) { src = gA; dst = AgT; } else { j -= AT; src = uA; dst = AuT; }
        int r = j >> 12, k = j & 4095;
        dst[j] = f2bf(src[k * 32 + r]);
    }
    const int AD = I_DIM * 32;
    for (int i = tid0; i < AD; i += stride) AdBf[i] = f2bf(dA[i]);
    // S4: B transposes -> [N][32] bf16
    const int TBI = I_DIM * 32, TBH = H_DIM * 32;
    for (int i = tid0; i < 2 * TBI + TBH; i += stride) {
        int j = i; const float* src; unsigned short* dst; int N;
        if (j < TBI) { src = gB; dst = BgT; N = I_DIM; }
        else if ((j -= TBI) < TBI) { src = uB; dst = BuT; N = I_DIM; }
        else { j -= TBI; src = dB; dst = BdT; N = H_DIM; }
        int n = j >> 5, r = j & 31;
        dst[j] = f2bf(src[r * N + n]);
    }
}

// ---------------- T = 0.02 * (x @ A): skinny M x 32 GEMM, bf16 out ---------------
__global__ __launch_bounds__(256) void k_T(
    const unsigned short* __restrict__ xbf,  // [M][H] bf16
    const unsigned short* __restrict__ AgT,  // [32][H] bf16
    const unsigned short* __restrict__ AuT,
    unsigned short* __restrict__ Tg,         // [M][32] bf16
    unsigned short* __restrict__ Tu)
{
    const unsigned short* AT = blockIdx.y ? AuT : AgT;
    unsigned short* T = blockIdx.y ? Tu : Tg;
    const int wid = threadIdx.x >> 6, lane = threadIdx.x & 63;
    const int base = blockIdx.x * 64 + wid * 16;
    const int l15 = lane & 15, kg = (lane >> 4) * 8;
    f32x4 acc0 = {}, acc1 = {};
    for (int k0 = 0; k0 < H_DIM; k0 += 32) {
        short8 af = *(const short8*)&xbf[(size_t)(base + l15) * H_DIM + k0 + kg];
        short8 b0 = *(const short8*)&AT[(size_t)l15 * H_DIM + k0 + kg];
        short8 b1 = *(const short8*)&AT[(size_t)(16 + l15) * H_DIM + k0 + kg];
        acc0 = __builtin_amdgcn_mfma_f32_16x16x32_bf16(af, b0, acc0, 0, 0, 0);
        acc1 = __builtin_amdgcn_mfma_f32_16x16x32_bf16(af, b1, acc1, 0, 0, 0);
    }
    const int q4 = lane >> 4;
#pragma unroll
    for (int t = 0; t < 4; t++) {
        int m = base + q4 * 4 + t;
        T[m * 32 + l15]      = f2bf(acc0[t] * 0.02f);
        T[m * 32 + 16 + l15] = f2bf(acc1[t] * 0.02f);
    }
}

// ---------------- W_eff prep for DOWN only (dequant + LR fold, bf16) --------------
__global__ __launch_bounds__(256) void k_wprep(
    const unsigned short* __restrict__ BT,   // [Nw][32] bf16
    const unsigned short* __restrict__ Abf,  // [Kw][32] bf16
    const int* __restrict__ q,               // [Nw][Kw] int32
    const float* __restrict__ scale,         // [Nw]
    unsigned short* __restrict__ W,          // [Nw][Kw] bf16 out
    int Nw, int Kw)
{
    __shared__ unsigned short As[128 * 32];
    __shared__ unsigned short Bs[128 * 32];
    const int tid = threadIdx.x, wid = tid >> 6, lane = tid & 63;
    const int wr = wid >> 1, wc = wid & 1;
    const int brow = blockIdx.y * 128;
    const int bcol = blockIdx.x * 128;
    const int srow = wid * 16 + (lane >> 2), scol = (lane & 3) * 8;

    gload16(BT + (size_t)(brow + srow) * 32 + scol,        &As[wid * 512]);
    gload16(BT + (size_t)(brow + 64 + srow) * 32 + scol,   &As[wid * 512 + 2048]);
    gload16(Abf + (size_t)(bcol + srow) * 32 + scol,       &Bs[wid * 512]);
    gload16(Abf + (size_t)(bcol + 64 + srow) * 32 + scol,  &Bs[wid * 512 + 2048]);
    __syncthreads();

    const int fr = lane & 15, kg = (lane >> 4) * 8;
    f32x4 acc[4][4] = {};
    short8 af[4], bfr[4];
#pragma unroll
    for (int i = 0; i < 4; i++)
        af[i] = *(const short8*)&As[(wr * 64 + i * 16 + fr) * 32 + kg];
#pragma unroll
    for (int j = 0; j < 4; j++)
        bfr[j] = *(const short8*)&Bs[(wc * 64 + j * 16 + fr) * 32 + kg];
#pragma unroll
    for (int i = 0; i < 4; i++)
#pragma unroll
        for (int j = 0; j < 4; j++)
            acc[i][j] = __builtin_amdgcn_mfma_f32_16x16x32_bf16(af[i], bfr[j], acc[i][j], 0, 0, 0);

    const int q4 = lane >> 4;
#pragma unroll
    for (int i = 0; i < 4; i++) {
#pragma unroll
        for (int t = 0; t < 4; t++) {
            int n = brow + wr * 64 + i * 16 + q4 * 4 + t;
            float sc = scale[n] * 0.005f;
#pragma unroll
            for (int j = 0; j < 4; j++) {
                int k = bcol + wc * 64 + j * 16 + fr;
                size_t off = (size_t)n * Kw + k;
                float w = ((float)q[off] - 7.5f) * sc + 0.02f * acc[i][j][t];
                W[off] = f2bf(w);
            }
        }
    }
}

// =============== fused gate+up i8 GEMM (4-window halved-R5 schedule) ===============
// h = silu(deq(x_i8@Wg8^T) + Tg@BgT^T) * (deq(x_i8@Wu8^T) + Tu@BuT^T)
// Block: 256 M x 128 N. LDS/buf: A 256x64 i8 (16K), Bg (16384), Bu (24576);
// 2 bufs = 64KB.
// BANK-CONFLICT FIX (R17: 3.47e7 8-way conflicts): XOR slot swizzle
// phys_slot = logical_slot ^ ((row>>1)&3) within each 64B row. Read side:
// row bits 1-2 come only from l15 -> per-lane constant folded into aRd/bRd.
// Stage side (rule 21): LDS dest stays LINEAR; global SOURCE col pre-swizzled
// by (lane>>3)&3 (= bits 1-2 of the thread's staged row). 2-way residual = free.
__global__ __launch_bounds__(512, 1) void k_gemmfu8(
    const char* __restrict__ Xq,             // [M][K] i8
    const char* __restrict__ Wg8,            // [NI][K] i8
    const char* __restrict__ Wu8,
    const unsigned short* __restrict__ Tg,   // [M][32] bf16 (0.02 folded)
    const unsigned short* __restrict__ Tu,
    const unsigned short* __restrict__ BgT,  // [NI][32] bf16
    const unsigned short* __restrict__ BuT,
    const float* __restrict__ gs, const float* __restrict__ us,
    unsigned short* __restrict__ H,          // [M][NI] bf16
    int M, int NI, int K)
{
    extern __shared__ char dynsmem[];
    char* smem = dynsmem;   // 64 KiB
    const int tid = threadIdx.x, wid = tid >> 6, lane = tid & 63;
    const int wr = wid >> 2, wc = wid & 3;

    // T1: bijective XCD swizzle, M-major (R12-proven)
    const int gx = NI >> 7;
    const int nwg = gx * (M >> 8);
    int orig = blockIdx.y * gx + blockIdx.x;
    int q8 = nwg >> 3, r8 = nwg & 7;
    int xcd = orig & 7, lid = orig >> 3;
    int wg = (xcd < r8 ? xcd * (q8 + 1) : r8 * (q8 + 1) + (xcd - r8) * q8) + lid;
    const int bcol = (wg % gx) << 7;
    const int brow = (wg / gx) << 8;

    // staging sources: line = 128 rows x 64B; thread t: row t>>2,
    // PRE-SWIZZLED source slot (t&3) ^ ((t>>3)&3)  [= bits 1-2 of staged row]
    const int srow = wid * 16 + (lane >> 2);
    const int scolB = ((lane & 3) ^ ((lane >> 3) & 3)) * 16;
    const char* aSrc  = Xq  + (size_t)(brow + srow) * K + scolB;
    const char* bgSrc = Wg8 + (size_t)(bcol + srow) * K + scolB;
    const char* buSrc = Wu8 + (size_t)(bcol + srow) * K + scolB;
    const int ldwB = wid * 1024;

    i32x4 acc[8][4];
#pragma unroll
    for (int i = 0; i < 8; ++i)
#pragma unroll
        for (int j = 0; j < 4; ++j) acc[i][j] = (i32x4){0, 0, 0, 0};

    i32x4 A0f[4], A1f[4], BgAf[2], BgBf[2], Buf[2];
    const int l15 = lane & 15, q4b = lane >> 4;
    // swizzled read slot: q4b ^ ((l15>>1)&3), per-lane constant
    const int ps = (q4b ^ ((l15 >> 1) & 3)) * 16;
    const char* aRd = smem + (wr * 64 + l15) * 64 + ps;
    const char* bRd = smem + 16384 + (wc * 32 + l15) * 64 + ps;
    const int NT = K >> 6;   // 64

#define SA0(BB, k0) gload16(aSrc + (k0), smem + (BB)*32768 + ldwB)
#define SA1(BB, k0) gload16(aSrc + 128*(size_t)K + (k0), smem + (BB)*32768 + 8192 + ldwB)
#define SBG(BB, k0) gload16(bgSrc + (k0), smem + (BB)*32768 + 16384 + ldwB)
#define SBU(BB, k0) gload16(buSrc + (k0), smem + (BB)*32768 + 24576 + ldwB)
#define LDA0(BB) { _Pragma("unroll") for (int i4 = 0; i4 < 4; ++i4) \
    A0f[i4] = *(const i32x4*)(aRd + (BB)*32768 + i4*1024); }
#define LDA1(BB) { _Pragma("unroll") for (int i4 = 0; i4 < 4; ++i4) \
    A1f[i4] = *(const i32x4*)(aRd + (BB)*32768 + 8192 + i4*1024); }
#define LDBG(SET, BB) { _Pragma("unroll") for (int j2 = 0; j2 < 2; ++j2) \
    SET[j2] = *(const i32x4*)(bRd + (BB)*32768 + j2*1024); }
#define LDBU(BB) { _Pragma("unroll") for (int j2 = 0; j2 < 2; ++j2) \
    Buf[j2] = *(const i32x4*)(bRd + (BB)*32768 + 8192 + j2*1024); }
#define MFI(AF, BF, IH, JB) { __builtin_amdgcn_s_setprio(1); \
    _Pragma("unroll") for (int i4 = 0; i4 < 4; ++i4) \
    _Pragma("unroll") for (int j2 = 0; j2 < 2; ++j2) \
        acc[(IH)*4+i4][(JB)*2+j2] = __builtin_amdgcn_mfma_i32_16x16x64_i8( \
            AF[i4], BF[j2], acc[(IH)*4+i4][(JB)*2+j2], 0, 0, 0); \
    __builtin_amdgcn_s_setprio(0); }
#define BARR() __builtin_amdgcn_s_barrier()

// One K-tile. BGC: this tile's Bg reg set; BGN: next tile's.
// S2: stage tile t+2 (k2). CERT: 0 none / 1 vmcnt(2) / 2 vmcnt(0). RN: next reads.
#define FTILE(BB, BGC, BGN, k2, S2, CERT, RN) { \
    LDBU(BB); \
    BARR(); \
    MFI(A0f, BGC, 0, 0); \
    LDA1(BB); \
    BARR(); \
    if (S2) { SA0(BB, k2); SBG(BB, k2); } \
    MFI(A0f, Buf, 0, 1); \
    if (CERT == 1) asm volatile("s_waitcnt vmcnt(2)" ::: "memory"); \
    if (CERT == 2) asm volatile("s_waitcnt vmcnt(0)" ::: "memory"); \
    BARR(); \
    if (S2) { SBU(BB, k2); } \
    MFI(A1f, Buf, 1, 1); \
    if (RN) { LDA0(1-(BB)); LDBG(BGN, 1-(BB)); } \
    BARR(); \
    if (S2) { SA1(BB, k2); } \
    MFI(A1f, BGC, 1, 0); \
}

    // prologue: stage tiles 0 and 1 (8 lines); wait tile 0; read its A0/Bg.
    SA0(0, 0); SBG(0, 0); SBU(0, 0); SA1(0, 0);
    SA0(1, 64); SBG(1, 64); SBU(1, 64); SA1(1, 64);
    asm volatile("s_waitcnt vmcnt(4)" ::: "memory");
    BARR();
    LDA0(0); LDBG(BgAf, 0);

    for (int u = 0; u < (NT - 2) / 2; ++u) {
        const int k2a = (2 * u + 2) << 6, k2b = (2 * u + 3) << 6;
        FTILE(0, BgAf, BgBf, k2a, 1, 1, 1);
        FTILE(1, BgBf, BgAf, k2b, 1, 1, 1);
    }
    FTILE(0, BgAf, BgBf, 0, 0, 2, 1);   // tile NT-2
    FTILE(1, BgBf, BgAf, 0, 0, 0, 0);   // tile NT-1

#undef FTILE
#undef BARR
#undef MFI
#undef LDBU
#undef LDBG
#undef LDA1
#undef LDA0
#undef SBU
#undef SBG
#undef SA1
#undef SA0

    // ---- epilogue: LR correction via bf16 MFMA, silu, store ----
    __builtin_amdgcn_s_barrier();   // all K-loop LDS reads complete block-wide
    {
        const int scolH = (lane & 3) * 8;   // bf16 elems (16B), linear
        gload16(Tg + (size_t)(brow + srow) * 32 + scolH,        smem + ldwB);
        gload16(Tg + (size_t)(brow + 128 + srow) * 32 + scolH,  smem + 8192 + ldwB);
        gload16(Tu + (size_t)(brow + srow) * 32 + scolH,        smem + 16384 + ldwB);
        gload16(Tu + (size_t)(brow + 128 + srow) * 32 + scolH,  smem + 24576 + ldwB);
        gload16(BgT + (size_t)(bcol + srow) * 32 + scolH,       smem + 32768 + ldwB);
        gload16(BuT + (size_t)(bcol + srow) * 32 + scolH,       smem + 40960 + ldwB);
    }
    asm volatile("s_waitcnt vmcnt(0)" ::: "memory");
    __builtin_amdgcn_s_barrier();

    const int fr = l15;
    short8 BgF[2], BuF[2];
#pragma unroll
    for (int j2 = 0; j2 < 2; ++j2) {
        BgF[j2] = *(const short8*)(smem + 32768 + (wc * 32 + j2 * 16 + l15) * 64 + q4b * 16);
        BuF[j2] = *(const short8*)(smem + 40960 + (wc * 32 + j2 * 16 + l15) * 64 + q4b * 16);
    }
    float cg[2], cu[2];
#pragma unroll
    for (int j2 = 0; j2 < 2; ++j2) {
        int n = bcol + wc * 32 + j2 * 16 + fr;
        cg[j2] = gs[n] * QS;
        cu[j2] = us[n] * QS;
    }
    const int q4 = lane >> 4;
#pragma unroll
    for (int i = 0; i < 8; ++i) {
        int trow = (i >> 2) * 128 + wr * 64 + (i & 3) * 16 + l15;
        short8 tgf = *(const short8*)(smem + trow * 64 + q4b * 16);
        short8 tuf = *(const short8*)(smem + 16384 + trow * 64 + q4b * 16);
#pragma unroll
        for (int j2 = 0; j2 < 2; ++j2) {
            f32x4 ag, au;
#pragma unroll
            for (int t = 0; t < 4; ++t) {
                ag[t] = (float)acc[i][j2][t] * cg[j2];
                au[t] = (float)acc[i][2 + j2][t] * cu[j2];
            }
            ag = __builtin_amdgcn_mfma_f32_16x16x32_bf16(tgf, BgF[j2], ag, 0, 0, 0);
            au = __builtin_amdgcn_mfma_f32_16x16x32_bf16(tuf, BuF[j2], au, 0, 0, 0);
#pragma unroll
            for (int t = 0; t < 4; ++t) {
                int m = brow + (i >> 2) * 128 + wr * 64 + (i & 3) * 16 + q4 * 4 + t;
                int n = bcol + wc * 32 + j2 * 16 + fr;
                float g = ag[t];
                float s = g / (1.0f + __expf(-g));
                H[(size_t)m * NI + n] = f2bf(s * au[t]);
            }
        }
    }
}

// ================== bf16 GEMM machinery (R5 schedule) for DOWN ====================
#define STG(p, k0, doff) gload16((p) + (k0), smem + (doff) + ldw)
#define LDA8(dst, P, IH) { _Pragma("unroll") \
    for (int i4 = 0; i4 < 4; ++i4) dst[i4] = *(const short8*)&(P)[(IH)*8192 + i4*1024]; }
#define LDB4(dst, P, JH) { _Pragma("unroll") \
    for (int j2 = 0; j2 < 2; ++j2) dst[j2] = *(const short8*)&(P)[(JH)*8192 + j2*1024]; }
#define MF8(AF, BF, IH, JH) { __builtin_amdgcn_s_setprio(1); \
    _Pragma("unroll") for (int i4 = 0; i4 < 4; ++i4) \
    _Pragma("unroll") for (int j2 = 0; j2 < 2; ++j2) \
        acc[(IH)*4+i4][(JH)*2+j2] = __builtin_amdgcn_mfma_f32_16x16x32_bf16( \
            AF[i4], BF[j2], acc[(IH)*4+i4][(JH)*2+j2], 0, 0, 0); \
    __builtin_amdgcn_s_setprio(0); }

#define TILE(BB, t, S2, SB0, CERT, RNEXT) { \
    const int kN = ((t) + 1) << 6, kN2 = ((t) + 2) << 6; \
    LDA8(afY, aP[BB][1], 0); LDB4(bfY, bP[BB][1], 0); \
    __builtin_amdgcn_s_barrier(); \
    if (SB0) { STG(bS[0], kN, (1-(BB))*32768 + 16384); \
               STG(bS[1], kN, (1-(BB))*32768 + 20480); } \
    MF8(afX, bfX, 0, 0); \
    LDB4(bfX, bP[BB][0], 1); \
    __builtin_amdgcn_s_barrier(); \
    MF8(afY, bfY, 0, 0); \
    LDB4(bfY, bP[BB][1], 1); \
    __builtin_amdgcn_s_barrier(); \
    if (S2) { STG(aS[0], kN2, (BB)*32768); STG(aS[1], kN2, (BB)*32768 + 4096); } \
    MF8(afX, bfX, 0, 1); \
    LDA8(afX, aP[BB][0], 1); \
    __builtin_amdgcn_s_barrier(); \
    MF8(afY, bfY, 0, 1); \
    LDA8(afY, aP[BB][1], 1); \
    if (CERT == 1) asm volatile("s_waitcnt vmcnt(2)" ::: "memory"); \
    if (CERT == 2) asm volatile("s_waitcnt vmcnt(0)" ::: "memory"); \
    __builtin_amdgcn_s_barrier(); \
    if (S2) { STG(bS[2], kN2, (BB)*32768 + 24576); STG(bS[3], kN2, (BB)*32768 + 28672); } \
    MF8(afX, bfX, 1, 1); \
    LDB4(bfX, bP[BB][0], 0); \
    __builtin_amdgcn_s_barrier(); \
    MF8(afY, bfY, 1, 1); \
    LDB4(bfY, bP[BB][1], 0); \
    __builtin_amdgcn_s_barrier(); \
    if (S2) { STG(aS[2], kN2, (BB)*32768 + 8192); STG(aS[3], kN2, (BB)*32768 + 12288); } \
    MF8(afX, bfX, 1, 0); \
    if (RNEXT) { LDA8(afX, aP[1-(BB)][0], 0); LDB4(bfX, bP[1-(BB)][0], 0); } \
    __builtin_amdgcn_s_barrier(); \
    MF8(afY, bfY, 1, 0); \
}

#define GEMM_BODY(K_) { \
    const int NT = (K_) >> 6; \
    STG(aS[0], 0, 0);      STG(aS[1], 0, 4096); \
    STG(bS[0], 0, 16384);  STG(bS[1], 0, 20480); \
    STG(bS[2], 0, 24576);  STG(bS[3], 0, 28672); \
    STG(aS[2], 0, 8192);   STG(aS[3], 0, 12288); \
    STG(aS[0], 64, 32768);         STG(aS[1], 64, 32768 + 4096); \
    STG(bS[2], 64, 32768 + 24576); STG(bS[3], 64, 32768 + 28672); \
    STG(aS[2], 64, 32768 + 8192);  STG(aS[3], 64, 32768 + 12288); \
    asm volatile("s_waitcnt vmcnt(6)" ::: "memory"); \
    __builtin_amdgcn_s_barrier(); \
    LDA8(afX, aP[0][0], 0); LDB4(bfX, bP[0][0], 0); \
    int t = 0; \
    for (; t + 4 <= NT; t += 2) { \
        TILE(0, t,     1, 1, 1, 1); \
        TILE(1, t + 1, 1, 1, 1, 1); \
    } \
    TILE(0, NT - 2, 0, 1, 2, 1); \
    TILE(1, NT - 1, 0, 0, 0, 0); \
}

// ---------------- down GEMM: C[M][N] = A[M][K] @ B[N][K]^T, f32 out --------------
__global__ __launch_bounds__(512, 1) void k_gemmdown(
    const unsigned short* __restrict__ A,   // [M][K] bf16 (h)
    const unsigned short* __restrict__ B,   // [N][K] bf16 (wd)
    float* __restrict__ C,                  // [M][N] f32
    int M, int N, int K)
{
    extern __shared__ char dynsmem[];
    unsigned short* smem = (unsigned short*)dynsmem;   // 128 KiB
    const int tid = threadIdx.x, wid = tid >> 6, lane = tid & 63;
    const int wr = wid >> 2, wc = wid & 3;

    const int gx = N >> 8;
    const int nwg = gx * (M >> 8);
    int orig = blockIdx.y * gx + blockIdx.x;
    int q8 = nwg >> 3, r8 = nwg & 7;
    int xcd = orig & 7, lid = orig >> 3;
    int wg = (xcd < r8 ? xcd * (q8 + 1) : r8 * (q8 + 1) + (xcd - r8) * q8) + lid;
    const int bcol = (wg % gx) << 8;
    const int brow = (wg / gx) << 8;

    const int rg = lane >> 3;
    const int ss = ((lane & 7) ^ rg) * 8;
    const unsigned short* aS[4];
    const unsigned short* bS[4];
#pragma unroll
    for (int c = 0; c < 4; c++) {
        int row = c * 64 + wid * 8 + rg;
        aS[c] = A + (size_t)(brow + row) * K + ss;
        bS[c] = B + (size_t)(bcol + row) * K + ss;
    }
    const int ldw = wid * 512;

    f32x4 acc[8][4] = {};
    short8 afX[4], afY[4], bfX[2], bfY[2];
    const int fr = lane & 15, qk = lane >> 4, f7 = fr & 7;

    const unsigned short* aP[2][2];
    const unsigned short* bP[2][2];
#pragma unroll
    for (int b = 0; b < 2; ++b)
#pragma unroll
        for (int kk = 0; kk < 2; ++kk) {
            int swz = (((kk << 2) | qk) ^ f7) << 3;
            aP[b][kk] = smem + b * 32768 + (wr * 64 + fr) * 64 + swz;
            bP[b][kk] = smem + b * 32768 + 16384 + (wc * 32 + fr) * 64 + swz;
        }

    GEMM_BODY(K);

    const int q4 = lane >> 4;
#pragma unroll
    for (int i = 0; i < 8; ++i) {
#pragma unroll
        for (int j = 0; j < 4; ++j) {
#pragma unroll
            for (int tt = 0; tt < 4; ++tt) {
                int m = brow + (i >> 2) * 128 + wr * 64 + (i & 3) * 16 + q4 * 4 + tt;
                int n = bcol + (j >> 1) * 128 + wc * 32 + (j & 1) * 16 + fr;
                C[(size_t)m * N + n] = acc[i][j][tt];
            }
        }
    }
}

// ---------------- host launch ----------------
extern "C" void kernel_launch(void* const* d_in, const int* in_sizes, int n_in,
                              void* d_out, int out_size, void* d_ws, size_t ws_size,
                              hipStream_t stream) {
    (void)in_sizes; (void)n_in; (void)out_size; (void)ws_size;
    const float* x          = (const float*)d_in[0];
    const int*   gate_q     = (const int*)d_in[1];
    const float* gate_scale = (const float*)d_in[2];
    const float* gate_A     = (const float*)d_in[3];
    const float* gate_B     = (const float*)d_in[4];
    const int*   up_q       = (const int*)d_in[5];
    const float* up_scale   = (const float*)d_in[6];
    const float* up_A       = (const float*)d_in[7];
    const float* up_B       = (const float*)d_in[8];
    const int*   down_q     = (const int*)d_in[9];
    const float* down_scale = (const float*)d_in[10];
    const float* down_A     = (const float*)d_in[11];
    const float* down_B     = (const float*)d_in[12];

    char* ws = (char*)d_ws;
    size_t off = 0;
    auto alloc = [&](size_t bytes) {
        void* p = ws + off; off += (bytes + 255) & ~(size_t)255; return p;
    };
    unsigned short* xbf  = (unsigned short*)alloc((size_t)M_TOK * H_DIM * 2);
    char*           xi8  = (char*)alloc((size_t)M_TOK * H_DIM);
    char*           Wg8  = (char*)alloc((size_t)I_DIM * H_DIM);
    char*           Wu8  = (char*)alloc((size_t)I_DIM * H_DIM);
    unsigned short* wdm  = (unsigned short*)alloc((size_t)H_DIM * I_DIM * 2);
    unsigned short* hbuf = (unsigned short*)alloc((size_t)M_TOK * I_DIM * 2);
    unsigned short* Tg   = (unsigned short*)alloc((size_t)M_TOK * 32 * 2);
    unsigned short* Tu   = (unsigned short*)alloc((size_t)M_TOK * 32 * 2);
    unsigned short* AgT  = (unsigned short*)alloc((size_t)32 * H_DIM * 2);
    unsigned short* AuT  = (unsigned short*)alloc((size_t)32 * H_DIM * 2);
    unsigned short* AdBf = (unsigned short*)alloc((size_t)I_DIM * 32 * 2);
    unsigned short* BgT  = (unsigned short*)alloc((size_t)I_DIM * 32 * 2);
    unsigned short* BuT  = (unsigned short*)alloc((size_t)I_DIM * 32 * 2);
    unsigned short* BdT  = (unsigned short*)alloc((size_t)H_DIM * 32 * 2);

    (void)hipFuncSetAttribute((const void*)k_gemmfu8,
        hipFuncAttributeMaxDynamicSharedMemorySize, 65536);
    (void)hipFuncSetAttribute((const void*)k_gemmdown,
        hipFuncAttributeMaxDynamicSharedMemorySize, 131072);

    k_prep_all<<<2048, 256, 0, stream>>>(x, gate_q, up_q, gate_A, up_A, down_A,
                                         gate_B, up_B, down_B,
                                         xbf, xi8, Wg8, Wu8, AgT, AuT, AdBf,
                                         BgT, BuT, BdT);

    // Tg/Tu = 0.02 * (x @ A)
    k_T<<<dim3(M_TOK / 64, 2), 256, 0, stream>>>(xbf, AgT, AuT, Tg, Tu);

    // down W_eff (bf16, LR folded)
    k_wprep<<<dim3(I_DIM / 128, H_DIM / 128), 256, 0, stream>>>(
        BdT, AdBf, down_q, down_scale, wdm, H_DIM, I_DIM);

    // fused gate+up in i8 + LR epilogue -> h (bf16)
    k_gemmfu8<<<dim3(I_DIM / 128, M_TOK / 256), 512, 65536, stream>>>(
        xi8, Wg8, Wu8, Tg, Tu, BgT, BuT, gate_scale, up_scale,
        hbuf, M_TOK, I_DIM, H_DIM);

    // out = h @ Wd^T (f32)
    k_gemmdown<<<dim3(H_DIM / 256, M_TOK / 256), 512, 131072, stream>>>(
        hbuf, wdm, (float*)d_out, M_TOK, H_DIM, I_DIM);
}